// Round 6
// baseline (447.859 us; speedup 1.0000x reference)
//
#include <hip/hip_runtime.h>
#include <stdint.h>

#define LL long long

typedef short short8 __attribute__((ext_vector_type(8)));
typedef short short4v __attribute__((ext_vector_type(4)));
typedef float f32x4 __attribute__((ext_vector_type(4)));
typedef unsigned int uint2v __attribute__((ext_vector_type(2)));

__device__ __forceinline__ unsigned short f2bf(float f) {
  unsigned u = __float_as_uint(f);
  unsigned r = (u + 0x7fffu + ((u >> 16) & 1u)) >> 16;
  return (unsigned short)r;
}
__device__ __forceinline__ float bf2f(unsigned short h) {
  return __uint_as_float(((unsigned)h) << 16);
}

#define MFMA16(A, B, C) __builtin_amdgcn_mfma_f32_16x16x32_bf16(A, B, C, 0, 0, 0)

// ======================================================================
// Weight pre-transform: src fp32 [OC][IC][3][3] -> bf16 [9][IC/32][OC][32]
// ======================================================================
__global__ __launch_bounds__(256) void wtrans2(
    const float* __restrict__ src, unsigned short* __restrict__ dh,
    unsigned short* __restrict__ dl, int OC, int IC)
{
  const int i = blockIdx.x * 256 + threadIdx.x;
  if (i >= OC * IC * 9) return;
  const int off = i % 9;
  const int rest = i / 9;
  const int ic = rest % IC;
  const int oc = rest / IC;
  const float v = src[i];
  const unsigned short h = f2bf(v);
  const LL di = (((LL)off * (IC >> 5) + (ic >> 5)) * OC + oc) * 32 + (ic & 31);
  dh[di] = h;
  if (dl) dl[di] = f2bf(v - bf2f(h));
}

// ======================================================================
// transp: src fp32 [B][C][N] -> dh/dl bf16 CHUNKED [B][C/32][N][32]
// ======================================================================
__global__ __launch_bounds__(256) void transp(
    const float* __restrict__ src, unsigned short* __restrict__ dh,
    unsigned short* __restrict__ dl, int C, int N)
{
  __shared__ unsigned short sh[64 * 66];
  __shared__ unsigned short sl[64 * 66];
  const int t = threadIdx.x;
  const int b = blockIdx.z;
  const int n0 = blockIdx.x * 64, c0 = blockIdx.y * 64;
  {
    const int nl = t & 63, cl0 = t >> 6;
#pragma unroll
    for (int i = 0; i < 16; ++i) {
      const int cl = cl0 + 4 * i;
      const float v = src[((LL)b * C + c0 + cl) * N + n0 + nl];
      const unsigned short h = f2bf(v);
      sh[nl * 66 + cl] = h;
      sl[nl * 66 + cl] = f2bf(v - bf2f(h));
    }
  }
  __syncthreads();
  {
    const int cl = t & 63, nr0 = t >> 6;
    const int chunk = (c0 + cl) >> 5;   // c0 is a multiple of 64
    const int cin = cl & 31;
#pragma unroll
    for (int j = 0; j < 16; ++j) {
      const int nr = nr0 + 4 * j;
      const LL di = (((LL)b * (C >> 5) + chunk) * N + n0 + nr) * 32 + cin;
      dh[di] = sh[nr * 66 + cl];
      if (dl) dl[di] = sl[nr * 66 + cl];
    }
  }
}

// ======================================================================
// conv_qk_r: register-blocked direct-load implicit-GEMM 3x3 conv, bf16x2.
// wave = 32 px x 32 oc, acc[2][2]; K split -> disjoint fp32 partials.
// Fully branch-free taps: clamp addresses, mask values (incl. gy).
// ======================================================================
__global__ __launch_bounds__(256) void conv_qk_r(
    const unsigned short* __restrict__ xh, const unsigned short* __restrict__ xl,
    const unsigned short* __restrict__ wh, const unsigned short* __restrict__ wl,
    float* __restrict__ outp, int logW, int H, int C, int chunks_per)
{
  const int t = threadIdx.x, w = t >> 6, lane = t & 63;
  const int lo4 = lane & 15, hi4 = lane >> 4;
  const int b = blockIdx.z;
  const int W = 1 << logW;
  const int N = H * W;
  const int px0 = (blockIdx.x * 4 + w) * 32;   // 32-px group, wave-uniform row
  const int row = px0 >> logW;
  const int x0 = px0 & (W - 1);
  const int nch = C >> 5;
  const int ch0 = blockIdx.y * chunks_per;
  const short8 zero8 = {0, 0, 0, 0, 0, 0, 0, 0};

  f32x4 acc[2][2];
#pragma unroll
  for (int p = 0; p < 2; ++p)
#pragma unroll
    for (int ot = 0; ot < 2; ++ot) acc[p][ot] = (f32x4){0.f, 0.f, 0.f, 0.f};

  for (int ch = ch0; ch < ch0 + chunks_per; ++ch) {
    const LL xbase = ((LL)(b * nch + ch)) * N * 32 + hi4 * 8;
#pragma unroll
    for (int ky = 0; ky < 3; ++ky) {
      const int gy = row + ky - 1;
      const bool oky = (unsigned)gy < (unsigned)H;
      const int gyc = min(max(gy, 0), H - 1);
#pragma unroll
      for (int kx = 0; kx < 3; ++kx) {
        short8 Bh[2], Bl[2];
#pragma unroll
        for (int p = 0; p < 2; ++p) {
          const int gx = x0 + p * 16 + lo4 + kx - 1;
          const bool ok = oky && ((unsigned)gx < (unsigned)W);
          const int gxc = min(max(gx, 0), W - 1);
          const LL xoff = xbase + (LL)(gyc * W + gxc) * 32;
          const short8 bh = *(const short8*)(xh + xoff);
          const short8 bl = *(const short8*)(xl + xoff);
          Bh[p] = ok ? bh : zero8;
          Bl[p] = ok ? bl : zero8;
        }
        const int off = ky * 3 + kx;
        short8 Ah[2], Al[2];
#pragma unroll
        for (int ot = 0; ot < 2; ++ot) {
          const LL wi = ((LL)(off * nch + ch) * 32 + ot * 16 + lo4) * 32 + hi4 * 8;
          Ah[ot] = *(const short8*)(wh + wi);
          Al[ot] = *(const short8*)(wl + wi);
        }
#pragma unroll
        for (int p = 0; p < 2; ++p)
#pragma unroll
          for (int ot = 0; ot < 2; ++ot) {
            acc[p][ot] = MFMA16(Ah[ot], Bh[p], acc[p][ot]);
            acc[p][ot] = MFMA16(Ah[ot], Bl[p], acc[p][ot]);
            acc[p][ot] = MFMA16(Al[ot], Bh[p], acc[p][ot]);
          }
      }
    }
  }
  float* op = outp + (LL)blockIdx.y * 8 * N * 32;   // partial slab (B=8)
#pragma unroll
  for (int p = 0; p < 2; ++p)
#pragma unroll
    for (int ot = 0; ot < 2; ++ot) {
      const LL o = ((LL)b * N + px0 + p * 16 + lo4) * 32 + ot * 16 + hi4 * 4;
      *(f32x4*)(op + o) = acc[p][ot];
    }
}

// ======================================================================
// red_split: sum nparts fp32 partial slabs -> bf16 hi/lo pair buffers.
// ======================================================================
__global__ __launch_bounds__(256) void red_split(
    const float* __restrict__ src, unsigned short* __restrict__ dh,
    unsigned short* __restrict__ dl, int nparts, int n4)
{
  const int i = blockIdx.x * 256 + threadIdx.x;
  if (i >= n4) return;
  f32x4 a = ((const f32x4*)src)[i];
  for (int p = 1; p < nparts; ++p)
    a += ((const f32x4*)src)[(LL)p * n4 + i];
  short4v hv, lv;
#pragma unroll
  for (int j = 0; j < 4; ++j) {
    const unsigned short h = f2bf(a[j]);
    hv[j] = (short)h;
    lv[j] = (short)f2bf(a[j] - bf2f(h));
  }
  ((short4v*)dh)[i] = hv;
  ((short4v*)dl)[i] = lv;
}

// ======================================================================
// conv_v_r: 512-thread in-block K-split conv, single bf16 pass.
// Branch-free taps; per-ky batched loads (12 loads -> 12 MFMAs) so the
// compiler can pipeline ky+1 loads under ky MFMAs.
// Output CHUNKED v16 [b][nchunk=32][oc=256][32].
// ======================================================================
__global__ __launch_bounds__(512) void conv_v_r(
    const unsigned short* __restrict__ xh, const unsigned short* __restrict__ wt,
    unsigned short* __restrict__ out)
{
  __shared__ float sred[16][4][64];
  const int t = threadIdx.x, w = t >> 6, lane = t & 63;
  const int lo4 = lane & 15, hi4 = lane >> 4;
  const int b = blockIdx.z;
  const int kh = w >> 2, wsub = w & 3;
  const int row = blockIdx.x * 2 + (wsub & 1);        // 0..31
  const int ocb = blockIdx.y * 64 + (wsub >> 1) * 32; // wave oc base
  const short8 zero8 = {0, 0, 0, 0, 0, 0, 0, 0};

  f32x4 acc[2][2];
#pragma unroll
  for (int p = 0; p < 2; ++p)
#pragma unroll
    for (int o = 0; o < 2; ++o) acc[p][o] = (f32x4){0.f, 0.f, 0.f, 0.f};

  for (int ch = kh * 8; ch < kh * 8 + 8; ++ch) {
    const LL xchb = ((LL)(b * 16 + ch)) * 1024 * 32 + hi4 * 8;
#pragma unroll
    for (int ky = 0; ky < 3; ++ky) {
      const int gy = row + ky - 1;
      const bool oky = (unsigned)gy < 32u;
      const int gyc = min(max(gy, 0), 31);
      short8 Bt[3][2], At[3][2];
#pragma unroll
      for (int kx = 0; kx < 3; ++kx) {
#pragma unroll
        for (int p = 0; p < 2; ++p) {
          const int gx = p * 16 + lo4 + kx - 1;
          const bool ok = oky && ((unsigned)gx < 32u);
          const int gxc = min(max(gx, 0), 31);
          const short8 bv = *(const short8*)(xh + xchb + (LL)(gyc * 32 + gxc) * 32);
          Bt[kx][p] = ok ? bv : zero8;
        }
        const int off = ky * 3 + kx;
#pragma unroll
        for (int o = 0; o < 2; ++o)
          At[kx][o] = *(const short8*)(
              wt + ((LL)(off * 16 + ch) * 256 + ocb + o * 16 + lo4) * 32 + hi4 * 8);
      }
#pragma unroll
      for (int kx = 0; kx < 3; ++kx)
#pragma unroll
        for (int p = 0; p < 2; ++p)
#pragma unroll
          for (int o = 0; o < 2; ++o)
            acc[p][o] = MFMA16(At[kx][o], Bt[kx][p], acc[p][o]);
    }
  }
  if (w >= 4) {
#pragma unroll
    for (int p = 0; p < 2; ++p)
#pragma unroll
      for (int o = 0; o < 2; ++o)
#pragma unroll
        for (int r = 0; r < 4; ++r)
          sred[p * 8 + o * 4 + r][wsub][lane] = acc[p][o][r];
  }
  __syncthreads();
  if (w < 4) {
#pragma unroll
    for (int p = 0; p < 2; ++p)
#pragma unroll
      for (int o = 0; o < 2; ++o)
#pragma unroll
        for (int r = 0; r < 4; ++r) {
          const float v = acc[p][o][r] + sred[p * 8 + o * 4 + r][wsub][lane];
          const int oc = ocb + o * 16 + hi4 * 4 + r;
          out[(((LL)b * 32 + row) * 256 + oc) * 32 + p * 16 + lo4] = f2bf(v);
        }
  }
}

// ======================================================================
// cf[b][n] = sum_c x1[b][c][n] * wc[c]
// ======================================================================
__global__ __launch_bounds__(256) void cf_dot(
    const float* __restrict__ x1, const float* __restrict__ wc, float* __restrict__ cf)
{
  const int b = blockIdx.y;
  const int n = blockIdx.x * 256 + threadIdx.x;
  const float* xp = x1 + (LL)b * 256 * 4096 + n;
  float a = 0.f;
#pragma unroll 4
  for (int c = 0; c < 256; ++c)
    a = fmaf(xp[(LL)c * 4096], wc[c], a);
  cf[b * 4096 + n] = a;
}

// ======================================================================
// softmax over 4096 per batch
// ======================================================================
__global__ __launch_bounds__(1024) void cf_softmax(
    const float* __restrict__ cf, float* __restrict__ cfs)
{
  const int b = blockIdx.x, t = threadIdx.x;
  __shared__ float r1[16];
  __shared__ float r2[16];
  float v[4];
#pragma unroll
  for (int j = 0; j < 4; ++j) v[j] = cf[b * 4096 + t + 1024 * j];
  float mx = fmaxf(fmaxf(v[0], v[1]), fmaxf(v[2], v[3]));
#pragma unroll
  for (int k = 1; k <= 32; k <<= 1) mx = fmaxf(mx, __shfl_xor(mx, k));
  const int wv = t >> 6;
  if ((t & 63) == 0) r1[wv] = mx;
  __syncthreads();
  float m2 = r1[0];
#pragma unroll
  for (int i = 1; i < 16; ++i) m2 = fmaxf(m2, r1[i]);
  float e[4]; float s = 0.f;
#pragma unroll
  for (int j = 0; j < 4; ++j) { e[j] = __expf(v[j] - m2); s += e[j]; }
#pragma unroll
  for (int k = 1; k <= 32; k <<= 1) s += __shfl_xor(s, k);
  if ((t & 63) == 0) r2[wv] = s;
  __syncthreads();
  float s2 = 0.f;
#pragma unroll
  for (int i = 0; i < 16; ++i) s2 += r2[i];
  const float inv = 1.f / s2;
#pragma unroll
  for (int j = 0; j < 4; ++j) cfs[b * 4096 + t + 1024 * j] = e[j] * inv;
}

// ======================================================================
// T[b][c][dy*3+dx] = sum_{y,x} x1[b][c][y][x] * cfs[b][y+1-dy][x+1-dx]
// ======================================================================
__global__ __launch_bounds__(256) void ykern(
    const float* __restrict__ x1, const float* __restrict__ cfs, float* __restrict__ T)
{
  __shared__ float cl[6][64];
  const int chunk = blockIdx.x, b = blockIdx.y, t = threadIdx.x;
  for (int idx = t; idx < 384; idx += 256) {
    int lr = idx >> 6, col = idx & 63;
    int gr = chunk * 4 - 1 + lr;
    cl[lr][col] = ((unsigned)gr < 64u) ? cfs[b * 4096 + gr * 64 + col] : 0.f;
  }
  __syncthreads();
  const int c = t;
  float a[9];
#pragma unroll
  for (int k = 0; k < 9; ++k) a[k] = 0.f;
  const float* xp = x1 + ((LL)b * 256 + c) * 4096 + chunk * 256;
  for (int i = 0; i < 256; ++i) {
    float xv = xp[i];
    int yl = i >> 6, col = i & 63;
#pragma unroll
    for (int dy = 0; dy < 3; ++dy) {
      int lr = yl + 2 - dy;
#pragma unroll
      for (int dx = 0; dx < 3; ++dx) {
        int cc = col + 1 - dx;
        float f = ((unsigned)cc < 64u) ? cl[lr][cc] : 0.f;
        a[dy * 3 + dx] = fmaf(xv, f, a[dy * 3 + dx]);
      }
    }
  }
#pragma unroll
  for (int k = 0; k < 9; ++k)
    atomicAdd(&T[((LL)b * 256 + c) * 9 + k], a[k]);
}

// ======================================================================
// pool_k: pool[b][oc] = wch[oc][:] . T[b][:]  (2304-dot)
// ======================================================================
__global__ __launch_bounds__(256) void pool_k(
    const float* __restrict__ T, const float* __restrict__ wch,
    float* __restrict__ pool)
{
  __shared__ __align__(16) float Tl[2304];
  const int b = blockIdx.y, ocg = blockIdx.x;
  const int t = threadIdx.x, w = t >> 6, lane = t & 63;
  for (int i = t; i < 2304; i += 256) Tl[i] = T[(LL)b * 2304 + i];
  __syncthreads();
  const float4* tp = (const float4*)Tl;
#pragma unroll
  for (int oi = 0; oi < 2; ++oi) {
    const int oc = ocg * 8 + w * 2 + oi;
    const float4* wp = (const float4*)(wch + (LL)oc * 2304);
    float a = 0.f;
#pragma unroll
    for (int j = 0; j < 9; ++j) {
      const int idx = lane + 64 * j;
      float4 w4 = wp[idx], t4 = tp[idx];
      a = fmaf(w4.x, t4.x, a); a = fmaf(w4.y, t4.y, a);
      a = fmaf(w4.z, t4.z, a); a = fmaf(w4.w, t4.w, a);
    }
#pragma unroll
    for (int k = 1; k <= 32; k <<= 1) a += __shfl_xor(a, k);
    if (lane == 0) pool[b * 256 + oc] = a;
  }
}

// ======================================================================
// chw_tail: t1 = wt1.pool + bt1 ; LN(32) ; relu ; cwp1 = 1 + wt2.t + bt2
// ======================================================================
__global__ __launch_bounds__(256) void chw_tail(
    const float* __restrict__ pool_g,
    const float* __restrict__ wt1, const float* __restrict__ bt1,
    const float* __restrict__ lng, const float* __restrict__ lnb,
    const float* __restrict__ wt2, const float* __restrict__ bt2,
    float* __restrict__ cwp1)
{
  const int b = blockIdx.x, t = threadIdx.x;
  __shared__ float pool[256];
  __shared__ float tt[32];
  pool[t] = pool_g[b * 256 + t];
  __syncthreads();
  if (t < 64) {
    float tv = 0.f;
    if (t < 32) {
      const float* wp = wt1 + (LL)t * 256;
      for (int c = 0; c < 256; ++c) tv = fmaf(wp[c], pool[c], tv);
      tv += bt1[t];
    }
    float s = tv;
#pragma unroll
    for (int k = 1; k <= 16; k <<= 1) s += __shfl_xor(s, k);
    float mu = s * (1.f / 32.f);
    float d = tv - mu;
    float vs = d * d;
#pragma unroll
    for (int k = 1; k <= 16; k <<= 1) vs += __shfl_xor(vs, k);
    float var = vs * (1.f / 32.f);
    if (t < 32) {
      float nrm = d / sqrtf(var + 1e-5f);
      float y = nrm * lng[t] + lnb[t];
      tt[t] = fmaxf(y, 0.f);
    }
  }
  __syncthreads();
  {
    float s2 = bt2[t];
    const float* wp = wt2 + (LL)t * 32;
#pragma unroll
    for (int i = 0; i < 32; ++i) s2 = fmaf(wp[i], tt[i], s2);
    cwp1[b * 256 + t] = 1.f + s2;
  }
}

// ======================================================================
// attn_stats: per (b,m) softmax max & inverse-sum over n=1024.
// ======================================================================
__global__ __launch_bounds__(256) void attn_stats(
    const unsigned short* __restrict__ qh_g, const unsigned short* __restrict__ ql_g,
    const unsigned short* __restrict__ kh_g, const unsigned short* __restrict__ kl_g,
    float* __restrict__ mxs, float* __restrict__ invl)
{
  const int t = threadIdx.x, w = t >> 6, lane = t & 63;
  const int lo4 = lane & 15, hi4 = lane >> 4;
  const int b = blockIdx.y, mc = blockIdx.x * 64;
  const float L2E = 1.4426950408889634f;

  short8 qh[4], ql[4];
#pragma unroll
  for (int mt = 0; mt < 4; ++mt) {
    const LL qa = ((LL)(b * 4096 + mc + mt * 16 + lo4)) * 32 + hi4 * 8;
    qh[mt] = *(const short8*)(qh_g + qa);
    ql[mt] = *(const short8*)(ql_g + qa);
  }

  float M[4], L[4];
#pragma unroll
  for (int mt = 0; mt < 4; ++mt) { M[mt] = -1e30f; L[mt] = 0.f; }

  for (int ns = 0; ns < 16; ++ns) {
    const int n = w * 256 + ns * 16 + lo4;
    const LL ka = ((LL)(b * 1024 + n)) * 32 + hi4 * 8;
    const short8 kh = *(const short8*)(kh_g + ka);
    const short8 kl = *(const short8*)(kl_g + ka);
#pragma unroll
    for (int mt = 0; mt < 4; ++mt) {
      f32x4 s = {0.f, 0.f, 0.f, 0.f};
      s = MFMA16(kl, qh[mt], s);
      s = MFMA16(kh, ql[mt], s);
      s = MFMA16(kh, qh[mt], s);
      float lm = fmaxf(fmaxf(s[0], s[1]), fmaxf(s[2], s[3]));
      float nM = fmaxf(M[mt], lm);
      float sc = exp2f((M[mt] - nM) * L2E);
      L[mt] = L[mt] * sc + exp2f((s[0] - nM) * L2E) + exp2f((s[1] - nM) * L2E)
                         + exp2f((s[2] - nM) * L2E) + exp2f((s[3] - nM) * L2E);
      M[mt] = nM;
    }
  }
#pragma unroll
  for (int mask = 16; mask <= 32; mask <<= 1) {
#pragma unroll
    for (int mt = 0; mt < 4; ++mt) {
      float oM = __shfl_xor(M[mt], mask), oL = __shfl_xor(L[mt], mask);
      float nM = fmaxf(M[mt], oM);
      L[mt] = L[mt] * exp2f((M[mt] - nM) * L2E) + oL * exp2f((oM - nM) * L2E);
      M[mt] = nM;
    }
  }
  __shared__ float sM[4][64], sL[4][64];
  if (lane < 16) {
#pragma unroll
    for (int mt = 0; mt < 4; ++mt) {
      sM[w][mt * 16 + lane] = M[mt];
      sL[w][mt * 16 + lane] = L[mt];
    }
  }
  __syncthreads();
  if (t < 64) {
    float Mg = sM[0][t], Lg = sL[0][t];
#pragma unroll
    for (int wv = 1; wv < 4; ++wv) {
      float oM = sM[wv][t], oL = sL[wv][t];
      float nM = fmaxf(Mg, oM);
      Lg = Lg * exp2f((Mg - nM) * L2E) + oL * exp2f((oM - nM) * L2E);
      Mg = nM;
    }
    mxs[b * 4096 + mc + t] = Mg * L2E;
    invl[b * 4096 + mc + t] = 1.f / Lg;
  }
}

// ======================================================================
// attn_pv: fused logits + softmax-apply + PV MFMA + epilogue.
// ======================================================================
__global__ __launch_bounds__(256) void attn_pv(
    const unsigned short* __restrict__ qh_g, const unsigned short* __restrict__ ql_g,
    const unsigned short* __restrict__ kh_g, const unsigned short* __restrict__ kl_g,
    const unsigned short* __restrict__ v16,
    const float* __restrict__ mxs, const float* __restrict__ invl,
    const float* __restrict__ x1, const float* __restrict__ cwp1,
    float* __restrict__ out)
{
  __shared__ __align__(16) unsigned short Pt[2][32][136];
  const int t = threadIdx.x, w = t >> 6, lane = t & 63;
  const int lo4 = lane & 15, hi4 = lane >> 4;
  const int b = blockIdx.y, mb = blockIdx.x * 32;
  const float L2E = 1.4426950408889634f;

  short8 qh[2], ql[2];
  float mxv[2], ilv[2];
#pragma unroll
  for (int mt = 0; mt < 2; ++mt) {
    const int m = mb + mt * 16 + lo4;
    const LL qa = ((LL)(b * 4096 + m)) * 32 + hi4 * 8;
    qh[mt] = *(const short8*)(qh_g + qa);
    ql[mt] = *(const short8*)(ql_g + qa);
    mxv[mt] = mxs[b * 4096 + m];
    ilv[mt] = invl[b * 4096 + m];
  }

  f32x4 acc[4][2];
#pragma unroll
  for (int ct = 0; ct < 4; ++ct)
#pragma unroll
    for (int mt = 0; mt < 2; ++mt) acc[ct][mt] = (f32x4){0.f, 0.f, 0.f, 0.f};

  // K fragments for nt=0
  short8 kh[2], kl[2];
#pragma unroll
  for (int ns = 0; ns < 2; ++ns) {
    const LL ka = ((LL)(b * 1024 + w * 32 + ns * 16 + lo4)) * 32 + hi4 * 8;
    kh[ns] = *(const short8*)(kh_g + ka);
    kl[ns] = *(const short8*)(kl_g + ka);
  }

  int buf = 0;
  for (int nt = 0; nt < 8; ++nt) {
    // prefetch next-nt K (wraps at 7; harmless dummy)
    short8 knh[2], knl[2];
    {
      const int ntn = (nt + 1) & 7;
#pragma unroll
      for (int ns = 0; ns < 2; ++ns) {
        const LL ka = ((LL)(b * 1024 + ntn * 128 + w * 32 + ns * 16 + lo4)) * 32 + hi4 * 8;
        knh[ns] = *(const short8*)(kh_g + ka);
        knl[ns] = *(const short8*)(kl_g + ka);
      }
    }
    // logits
    f32x4 s[2][2];
#pragma unroll
    for (int ns = 0; ns < 2; ++ns)
#pragma unroll
      for (int mt = 0; mt < 2; ++mt) {
        f32x4 z = {0.f, 0.f, 0.f, 0.f};
        z = MFMA16(kl[ns], qh[mt], z);
        z = MFMA16(kh[ns], ql[mt], z);
        z = MFMA16(kh[ns], qh[mt], z);
        s[ns][mt] = z;
      }
    // prefetch V for ks = 0,1 (independent of Pt)
    short8 vpre[2][4];
#pragma unroll
    for (int ks = 0; ks < 2; ++ks)
#pragma unroll
      for (int ct = 0; ct < 4; ++ct)
        vpre[ks][ct] = *(const short8*)(
            v16 + (((LL)b * 32 + nt * 4 + ks) * 256 + w * 64 + ct * 16 + lo4) * 32 + hi4 * 8);
    // softmax + pack + b64 LDS write
#pragma unroll
    for (int ns = 0; ns < 2; ++ns)
#pragma unroll
      for (int mt = 0; mt < 2; ++mt) {
        const int m_loc = mt * 16 + lo4;
        const int nl = w * 32 + ns * 16 + hi4 * 4;
        float p0 = exp2f(fmaf(s[ns][mt][0], L2E, -mxv[mt])) * ilv[mt];
        float p1 = exp2f(fmaf(s[ns][mt][1], L2E, -mxv[mt])) * ilv[mt];
        float p2 = exp2f(fmaf(s[ns][mt][2], L2E, -mxv[mt])) * ilv[mt];
        float p3 = exp2f(fmaf(s[ns][mt][3], L2E, -mxv[mt])) * ilv[mt];
        uint2v u;
        u[0] = (unsigned)f2bf(p0) | ((unsigned)f2bf(p1) << 16);
        u[1] = (unsigned)f2bf(p2) | ((unsigned)f2bf(p3) << 16);
        *(uint2v*)&Pt[buf][m_loc][nl] = u;
      }
    __syncthreads();
    // PV
#pragma unroll
    for (int ks = 0; ks < 4; ++ks) {
      short8 pb[2];
#pragma unroll
      for (int mt = 0; mt < 2; ++mt)
        pb[mt] = *(const short8*)&Pt[buf][mt * 16 + lo4][ks * 32 + hi4 * 8];
#pragma unroll
      for (int ct = 0; ct < 4; ++ct) {
        const short8 va = (ks < 2)
            ? vpre[ks][ct]
            : *(const short8*)(
                  v16 + (((LL)b * 32 + nt * 4 + ks) * 256 + w * 64 + ct * 16 + lo4) * 32 + hi4 * 8);
#pragma unroll
        for (int mt = 0; mt < 2; ++mt)
          acc[ct][mt] = MFMA16(va, pb[mt], acc[ct][mt]);
      }
    }
    buf ^= 1;
#pragma unroll
    for (int ns = 0; ns < 2; ++ns) { kh[ns] = knh[ns]; kl[ns] = knl[ns]; }
  }

#pragma unroll
  for (int ct = 0; ct < 4; ++ct)
#pragma unroll
    for (int mt = 0; mt < 2; ++mt) {
      const int m = mb + mt * 16 + lo4;
#pragma unroll
      for (int r = 0; r < 4; ++r) {
        const int c = w * 64 + ct * 16 + hi4 * 4 + r;
        const float cw = cwp1[b * 256 + c];
        const LL off = ((LL)(b * 256 + c)) * 4096 + m;
        out[off] = acc[ct][mt][r] + x1[off] * cw;
      }
    }
}

// ======================================================================
// launch
// ======================================================================
extern "C" void kernel_launch(void* const* d_in, const int* in_sizes, int n_in,
                              void* d_out, int out_size, void* d_ws, size_t ws_size,
                              hipStream_t stream) {
  const float* x1  = (const float*)d_in[0];
  const float* x2  = (const float*)d_in[1];
  const float* wq  = (const float*)d_in[2];
  const float* wk  = (const float*)d_in[3];
  const float* wv  = (const float*)d_in[4];
  const float* wc  = (const float*)d_in[5];
  const float* wch = (const float*)d_in[6];
  const float* wt1 = (const float*)d_in[7];
  const float* bt1 = (const float*)d_in[8];
  const float* lng = (const float*)d_in[9];
  const float* lnb = (const float*)d_in[10];
  const float* wt2 = (const float*)d_in[11];
  const float* bt2 = (const float*)d_in[12];
  float* outp = (float*)d_out;

  // ---- workspace (carve floats first, then shorts) ----
  float* ws   = (float*)d_ws;
  float* qtf  = ws;                      // q bf16 hi/lo region: 1,048,576 f
  float* ktf  = qtf + 1048576;           // k bf16 hi/lo region:   262,144 f
  float* mxsb = ktf + 262144;            //    32,768 f
  float* invb = mxsb + 32768;            //    32,768 f
  float* cfr  = invb + 32768;            //    32,768 f
  float* cfs  = cfr + 32768;             //    32,768 f
  float* Tb   = cfs + 32768;             //    18,432 f
  float* cwb  = Tb + 18432;              //     2,048 f
  unsigned short* sbase = (unsigned short*)(cwb + 2048);
  unsigned short* v16  = sbase;          // CHUNKED [8][32][256][32]  2,097,152 sh
  unsigned short* x1th = v16  + 2097152; // [8][8][4096][32]     8,388,608 sh
  unsigned short* x1tl = x1th + 8388608;
  unsigned short* x2th = x1tl + 8388608; // [8][16][1024][32]    4,194,304 sh
  unsigned short* x2tl = x2th + 4194304;
  unsigned short* wvt  = x2tl + 4194304; // [9][16][256][32]     1,179,648 sh
  unsigned short* wqh  = wvt  + 1179648; // [9][8][32][32]          73,728 sh
  unsigned short* wql  = wqh  + 73728;
  unsigned short* wkh  = wql  + 73728;   // [9][16][32][32]        147,456 sh
  unsigned short* wkl  = wkh  + 147456;

  // bf16 hi/lo attn operands (alias the fp32 regions exactly):
  unsigned short* qhg = (unsigned short*)qtf;   // [8][4096][32] sh
  unsigned short* qlg = qhg + 1048576;
  unsigned short* khg = (unsigned short*)ktf;   // [8][1024][32] sh
  unsigned short* klg = khg + 262144;

  // partial-sum aliases (time-disjoint with their hosts):
  float* ktp = qtf;            // 4 x [8][1024][32] f == q region (written later)
  float* qtp = (float*)x2th;   // 4 x [8][4096][32] f == x2th+x2tl (dead after k/v convs)

  // zero only the atomic-accumulated T buffer
  hipMemsetAsync(Tb, 0, (size_t)18432 * 4, stream);

  // weight pre-transforms ([9][IC/32][OC][32])
  wtrans2<<<dim3(4608), 256, 0, stream>>>(wv, wvt, nullptr, 256, 512);
  wtrans2<<<dim3(288),  256, 0, stream>>>(wq, wqh, wql, 32, 256);
  wtrans2<<<dim3(576),  256, 0, stream>>>(wk, wkh, wkl, 32, 512);

  // input transposes: [b][c][n] fp32 -> chunked [b][c/32][n][32] bf16 hi/lo
  transp<<<dim3(64, 4, 8), 256, 0, stream>>>(x1, x1th, x1tl, 256, 4096);
  transp<<<dim3(16, 8, 8), 256, 0, stream>>>(x2, x2th, x2tl, 512, 1024);

  // k conv (x2): 4-way K-split partials -> reduce+split into khg/klg
  conv_qk_r<<<dim3(8, 4, 8), 256, 0, stream>>>(x2th, x2tl, wkh, wkl, ktp, 5, 32, 512, 4);
  red_split<<<dim3(256), 256, 0, stream>>>(ktp, khg, klg, 4, 65536);

  // v conv (x2): consumes x2th; must precede q-conv (qtp aliases x2 region)
  conv_v_r<<<dim3(16, 4, 8), 512, 0, stream>>>(x2th, wvt, v16);

  // q conv (x1): 4-way K-split partials (alias x2 region) -> reduce+split
  conv_qk_r<<<dim3(32, 4, 8), 256, 0, stream>>>(x1th, x1tl, wqh, wql, qtp, 6, 64, 256, 2);
  red_split<<<dim3(1024), 256, 0, stream>>>(qtp, qhg, qlg, 4, 262144);

  // channel branch
  cf_dot<<<dim3(16, 8), 256, 0, stream>>>(x1, wc, cfr);
  cf_softmax<<<dim3(8), 1024, 0, stream>>>(cfr, cfs);
  ykern<<<dim3(16, 8), 256, 0, stream>>>(x1, cfs, Tb);
  pool_k<<<dim3(32, 8), 256, 0, stream>>>(Tb, wch, cfr);
  chw_tail<<<dim3(8), 256, 0, stream>>>(cfr, wt1, bt1, lng, lnb, wt2, bt2, cwb);

  // attention
  attn_stats<<<dim3(64, 8), 256, 0, stream>>>(qhg, qlg, khg, klg, mxsb, invb);
  attn_pv<<<dim3(128, 8), 256, 0, stream>>>(qhg, qlg, khg, klg, v16, mxsb, invb, x1, cwb, outp);
}

// Round 7
// 427.666 us; speedup vs baseline: 1.0472x; 1.0472x over previous
//
#include <hip/hip_runtime.h>
#include <stdint.h>

#define LL long long

typedef short short8 __attribute__((ext_vector_type(8)));
typedef float f32x4 __attribute__((ext_vector_type(4)));
typedef unsigned int uint2v __attribute__((ext_vector_type(2)));

__device__ __forceinline__ unsigned short f2bf(float f) {
  unsigned u = __float_as_uint(f);
  unsigned r = (u + 0x7fffu + ((u >> 16) & 1u)) >> 16;
  return (unsigned short)r;
}
__device__ __forceinline__ float bf2f(unsigned short h) {
  return __uint_as_float(((unsigned)h) << 16);
}

#define MFMA16(A, B, C) __builtin_amdgcn_mfma_f32_16x16x32_bf16(A, B, C, 0, 0, 0)

// ======================================================================
// Weight pre-transform: src fp32 [OC][IC][3][3] -> bf16 [9][IC/32][OC][32]
// ======================================================================
__global__ __launch_bounds__(256) void wtrans2(
    const float* __restrict__ src, unsigned short* __restrict__ dh,
    unsigned short* __restrict__ dl, int OC, int IC)
{
  const int i = blockIdx.x * 256 + threadIdx.x;
  if (i >= OC * IC * 9) return;
  const int off = i % 9;
  const int rest = i / 9;
  const int ic = rest % IC;
  const int oc = rest / IC;
  const float v = src[i];
  const unsigned short h = f2bf(v);
  const LL di = (((LL)off * (IC >> 5) + (ic >> 5)) * OC + oc) * 32 + (ic & 31);
  dh[di] = h;
  if (dl) dl[di] = f2bf(v - bf2f(h));
}

// ======================================================================
// transp: src fp32 [B][C][N] -> dh/dl bf16 CHUNKED [B][C/32][N][32]
// ======================================================================
__global__ __launch_bounds__(256) void transp(
    const float* __restrict__ src, unsigned short* __restrict__ dh,
    unsigned short* __restrict__ dl, int C, int N)
{
  __shared__ unsigned short sh[64 * 66];
  __shared__ unsigned short sl[64 * 66];
  const int t = threadIdx.x;
  const int b = blockIdx.z;
  const int n0 = blockIdx.x * 64, c0 = blockIdx.y * 64;
  {
    const int nl = t & 63, cl0 = t >> 6;
#pragma unroll
    for (int i = 0; i < 16; ++i) {
      const int cl = cl0 + 4 * i;
      const float v = src[((LL)b * C + c0 + cl) * N + n0 + nl];
      const unsigned short h = f2bf(v);
      sh[nl * 66 + cl] = h;
      sl[nl * 66 + cl] = f2bf(v - bf2f(h));
    }
  }
  __syncthreads();
  {
    const int cl = t & 63, nr0 = t >> 6;
    const int chunk = (c0 + cl) >> 5;   // c0 is a multiple of 64
    const int cin = cl & 31;
#pragma unroll
    for (int j = 0; j < 16; ++j) {
      const int nr = nr0 + 4 * j;
      const LL di = (((LL)b * (C >> 5) + chunk) * N + n0 + nr) * 32 + cin;
      dh[di] = sh[nr * 66 + cl];
      if (dl) dl[di] = sl[nr * 66 + cl];
    }
  }
}

// ======================================================================
// conv_qk_s<NW>: in-block FULL K-split 3x3 conv, bf16x2, NW waves,
// one 32-ch chunk per wave (C = NW*32). LDS all-wave reduction, then
// bf16 hi/lo split written DIRECTLY (replaces red_split).
// Tile = 32 px x 32 oc per block. q: NW=8, k: NW=16.
// ======================================================================
template<int NW>
__global__ __launch_bounds__(NW * 64) void conv_qk_s(
    const unsigned short* __restrict__ xh, const unsigned short* __restrict__ xl,
    const unsigned short* __restrict__ wh, const unsigned short* __restrict__ wl,
    unsigned short* __restrict__ dh, unsigned short* __restrict__ dl,
    int logW, int H)
{
  __shared__ float sred[NW][16][64];
  const int t = threadIdx.x, w = t >> 6, lane = t & 63;
  const int lo4 = lane & 15, hi4 = lane >> 4;
  const int b = blockIdx.z;
  const int W = 1 << logW;
  const int N = H * W;
  const int px0 = blockIdx.x * 32;
  const int row = px0 >> logW;       // wave-uniform (32 px within one row)
  const int x0 = px0 & (W - 1);
  const int ch = w;                  // one chunk per wave
  const short8 zero8 = {0, 0, 0, 0, 0, 0, 0, 0};

  f32x4 acc[2][2];
#pragma unroll
  for (int p = 0; p < 2; ++p)
#pragma unroll
    for (int ot = 0; ot < 2; ++ot) acc[p][ot] = (f32x4){0.f, 0.f, 0.f, 0.f};

  const LL xbase = ((LL)(b * NW + ch)) * N * 32 + hi4 * 8;
#pragma unroll
  for (int ky = 0; ky < 3; ++ky) {
    const int gy = row + ky - 1;
    const bool oky = (unsigned)gy < (unsigned)H;
    const int gyc = min(max(gy, 0), H - 1);
#pragma unroll
    for (int kx = 0; kx < 3; ++kx) {
      short8 Bh[2], Bl[2];
#pragma unroll
      for (int p = 0; p < 2; ++p) {
        const int gx = x0 + p * 16 + lo4 + kx - 1;
        const bool ok = oky && ((unsigned)gx < (unsigned)W);
        const int gxc = min(max(gx, 0), W - 1);
        const LL xoff = xbase + (LL)(gyc * W + gxc) * 32;
        const short8 bh = *(const short8*)(xh + xoff);
        const short8 bl = *(const short8*)(xl + xoff);
        Bh[p] = ok ? bh : zero8;
        Bl[p] = ok ? bl : zero8;
      }
      const int off = ky * 3 + kx;
      short8 Ah[2], Al[2];
#pragma unroll
      for (int ot = 0; ot < 2; ++ot) {
        const LL wi = ((LL)(off * NW + ch) * 32 + ot * 16 + lo4) * 32 + hi4 * 8;
        Ah[ot] = *(const short8*)(wh + wi);
        Al[ot] = *(const short8*)(wl + wi);
      }
#pragma unroll
      for (int p = 0; p < 2; ++p)
#pragma unroll
        for (int ot = 0; ot < 2; ++ot) {
          acc[p][ot] = MFMA16(Ah[ot], Bh[p], acc[p][ot]);
          acc[p][ot] = MFMA16(Ah[ot], Bl[p], acc[p][ot]);
          acc[p][ot] = MFMA16(Al[ot], Bh[p], acc[p][ot]);
        }
    }
  }
  // dump all partials to LDS
#pragma unroll
  for (int p = 0; p < 2; ++p)
#pragma unroll
    for (int ot = 0; ot < 2; ++ot)
#pragma unroll
      for (int r = 0; r < 4; ++r)
        sred[w][p * 8 + ot * 4 + r][lane] = acc[p][ot][r];
  __syncthreads();
  // each wave reduces 16/NW slots and writes bf16 hi/lo directly
  constexpr int SPW = 16 / NW;
#pragma unroll
  for (int si = 0; si < SPW; ++si) {
    const int slot = w * SPW + si;
    float v = sred[0][slot][lane];
#pragma unroll
    for (int j = 1; j < NW; ++j) v += sred[j][slot][lane];
    const int p = slot >> 3, ot = (slot >> 2) & 1, r = slot & 3;
    const LL di = ((LL)b * N + px0 + p * 16 + lo4) * 32 + ot * 16 + hi4 * 4 + r;
    const unsigned short h = f2bf(v);
    dh[di] = h;
    dl[di] = f2bf(v - bf2f(h));
  }
}

// ======================================================================
// conv_v_s: in-block 4-way K-split conv, single bf16 pass, 512 thr.
// 8 waves = 2 rows x 4 K-parts (4 ch each); LDS all-wave reduction.
// Output CHUNKED v16 [b][nchunk=32][oc=256][32] (row == nchunk).
// ======================================================================
__global__ __launch_bounds__(512) void conv_v_s(
    const unsigned short* __restrict__ xh, const unsigned short* __restrict__ wt,
    unsigned short* __restrict__ out)
{
  __shared__ float sred[8][16][64];
  const int t = threadIdx.x, w = t >> 6, lane = t & 63;
  const int lo4 = lane & 15, hi4 = lane >> 4;
  const int b = blockIdx.z;
  const int tile = w & 1, kp = w >> 1;
  const int row = blockIdx.x * 2 + tile;              // 0..31
  const int ocb = blockIdx.y * 32;                    // 8 oc32 tiles
  const short8 zero8 = {0, 0, 0, 0, 0, 0, 0, 0};

  f32x4 acc[2][2];
#pragma unroll
  for (int p = 0; p < 2; ++p)
#pragma unroll
    for (int o = 0; o < 2; ++o) acc[p][o] = (f32x4){0.f, 0.f, 0.f, 0.f};

  for (int ch = kp * 4; ch < kp * 4 + 4; ++ch) {
    const LL xchb = ((LL)(b * 16 + ch)) * 1024 * 32 + hi4 * 8;
#pragma unroll
    for (int ky = 0; ky < 3; ++ky) {
      const int gy = row + ky - 1;
      const bool oky = (unsigned)gy < 32u;
      const int gyc = min(max(gy, 0), 31);
#pragma unroll
      for (int kx = 0; kx < 3; ++kx) {
        short8 Bf[2];
#pragma unroll
        for (int p = 0; p < 2; ++p) {
          const int gx = p * 16 + lo4 + kx - 1;
          const bool ok = oky && ((unsigned)gx < 32u);
          const int gxc = min(max(gx, 0), 31);
          const short8 bv = *(const short8*)(xh + xchb + (LL)(gyc * 32 + gxc) * 32);
          Bf[p] = ok ? bv : zero8;
        }
        const int off = ky * 3 + kx;
        short8 Af[2];
#pragma unroll
        for (int o = 0; o < 2; ++o)
          Af[o] = *(const short8*)(
              wt + ((LL)(off * 16 + ch) * 256 + ocb + o * 16 + lo4) * 32 + hi4 * 8);
#pragma unroll
        for (int p = 0; p < 2; ++p)
#pragma unroll
          for (int o = 0; o < 2; ++o)
            acc[p][o] = MFMA16(Af[o], Bf[p], acc[p][o]);
      }
    }
  }
  // dump
#pragma unroll
  for (int p = 0; p < 2; ++p)
#pragma unroll
    for (int o = 0; o < 2; ++o)
#pragma unroll
      for (int r = 0; r < 4; ++r)
        sred[w][p * 8 + o * 4 + r][lane] = acc[p][o][r];
  __syncthreads();
  // wave w reduces tile (w&1), slot group (w>>1): 4 slots each
  const int tw = w & 1;
  const int rowt = blockIdx.x * 2 + tw;
#pragma unroll
  for (int si = 0; si < 4; ++si) {
    const int slot = (w >> 1) * 4 + si;
    const float v = sred[tw][slot][lane] + sred[2 + tw][slot][lane]
                  + sred[4 + tw][slot][lane] + sred[6 + tw][slot][lane];
    const int p = slot >> 3, o = (slot >> 2) & 1, r = slot & 3;
    const int oc = ocb + o * 16 + hi4 * 4 + r;
    out[(((LL)b * 32 + rowt) * 256 + oc) * 32 + p * 16 + lo4] = f2bf(v);
  }
}

// ======================================================================
// cf[b][n] = sum_c x1[b][c][n] * wc[c]
// ======================================================================
__global__ __launch_bounds__(256) void cf_dot(
    const float* __restrict__ x1, const float* __restrict__ wc, float* __restrict__ cf)
{
  const int b = blockIdx.y;
  const int n = blockIdx.x * 256 + threadIdx.x;
  const float* xp = x1 + (LL)b * 256 * 4096 + n;
  float a = 0.f;
#pragma unroll 4
  for (int c = 0; c < 256; ++c)
    a = fmaf(xp[(LL)c * 4096], wc[c], a);
  cf[b * 4096 + n] = a;
}

// ======================================================================
// softmax over 4096 per batch
// ======================================================================
__global__ __launch_bounds__(1024) void cf_softmax(
    const float* __restrict__ cf, float* __restrict__ cfs)
{
  const int b = blockIdx.x, t = threadIdx.x;
  __shared__ float r1[16];
  __shared__ float r2[16];
  float v[4];
#pragma unroll
  for (int j = 0; j < 4; ++j) v[j] = cf[b * 4096 + t + 1024 * j];
  float mx = fmaxf(fmaxf(v[0], v[1]), fmaxf(v[2], v[3]));
#pragma unroll
  for (int k = 1; k <= 32; k <<= 1) mx = fmaxf(mx, __shfl_xor(mx, k));
  const int wv = t >> 6;
  if ((t & 63) == 0) r1[wv] = mx;
  __syncthreads();
  float m2 = r1[0];
#pragma unroll
  for (int i = 1; i < 16; ++i) m2 = fmaxf(m2, r1[i]);
  float e[4]; float s = 0.f;
#pragma unroll
  for (int j = 0; j < 4; ++j) { e[j] = __expf(v[j] - m2); s += e[j]; }
#pragma unroll
  for (int k = 1; k <= 32; k <<= 1) s += __shfl_xor(s, k);
  if ((t & 63) == 0) r2[wv] = s;
  __syncthreads();
  float s2 = 0.f;
#pragma unroll
  for (int i = 0; i < 16; ++i) s2 += r2[i];
  const float inv = 1.f / s2;
#pragma unroll
  for (int j = 0; j < 4; ++j) cfs[b * 4096 + t + 1024 * j] = e[j] * inv;
}

// ======================================================================
// T[b][c][dy*3+dx] = sum_{y,x} x1[b][c][y][x] * cfs[b][y+1-dy][x+1-dx]
// ======================================================================
__global__ __launch_bounds__(256) void ykern(
    const float* __restrict__ x1, const float* __restrict__ cfs, float* __restrict__ T)
{
  __shared__ float cl[6][64];
  const int chunk = blockIdx.x, b = blockIdx.y, t = threadIdx.x;
  for (int idx = t; idx < 384; idx += 256) {
    int lr = idx >> 6, col = idx & 63;
    int gr = chunk * 4 - 1 + lr;
    cl[lr][col] = ((unsigned)gr < 64u) ? cfs[b * 4096 + gr * 64 + col] : 0.f;
  }
  __syncthreads();
  const int c = t;
  float a[9];
#pragma unroll
  for (int k = 0; k < 9; ++k) a[k] = 0.f;
  const float* xp = x1 + ((LL)b * 256 + c) * 4096 + chunk * 256;
  for (int i = 0; i < 256; ++i) {
    float xv = xp[i];
    int yl = i >> 6, col = i & 63;
#pragma unroll
    for (int dy = 0; dy < 3; ++dy) {
      int lr = yl + 2 - dy;
#pragma unroll
      for (int dx = 0; dx < 3; ++dx) {
        int cc = col + 1 - dx;
        float f = ((unsigned)cc < 64u) ? cl[lr][cc] : 0.f;
        a[dy * 3 + dx] = fmaf(xv, f, a[dy * 3 + dx]);
      }
    }
  }
#pragma unroll
  for (int k = 0; k < 9; ++k)
    atomicAdd(&T[((LL)b * 256 + c) * 9 + k], a[k]);
}

// ======================================================================
// pool_k: pool[b][oc] = wch[oc][:] . T[b][:]  (2304-dot)
// ======================================================================
__global__ __launch_bounds__(256) void pool_k(
    const float* __restrict__ T, const float* __restrict__ wch,
    float* __restrict__ pool)
{
  __shared__ __align__(16) float Tl[2304];
  const int b = blockIdx.y, ocg = blockIdx.x;
  const int t = threadIdx.x, w = t >> 6, lane = t & 63;
  for (int i = t; i < 2304; i += 256) Tl[i] = T[(LL)b * 2304 + i];
  __syncthreads();
  const float4* tp = (const float4*)Tl;
#pragma unroll
  for (int oi = 0; oi < 2; ++oi) {
    const int oc = ocg * 8 + w * 2 + oi;
    const float4* wp = (const float4*)(wch + (LL)oc * 2304);
    float a = 0.f;
#pragma unroll
    for (int j = 0; j < 9; ++j) {
      const int idx = lane + 64 * j;
      float4 w4 = wp[idx], t4 = tp[idx];
      a = fmaf(w4.x, t4.x, a); a = fmaf(w4.y, t4.y, a);
      a = fmaf(w4.z, t4.z, a); a = fmaf(w4.w, t4.w, a);
    }
#pragma unroll
    for (int k = 1; k <= 32; k <<= 1) a += __shfl_xor(a, k);
    if (lane == 0) pool[b * 256 + oc] = a;
  }
}

// ======================================================================
// chw_tail: t1 = wt1.pool + bt1 ; LN(32) ; relu ; cwp1 = 1 + wt2.t + bt2
// ======================================================================
__global__ __launch_bounds__(256) void chw_tail(
    const float* __restrict__ pool_g,
    const float* __restrict__ wt1, const float* __restrict__ bt1,
    const float* __restrict__ lng, const float* __restrict__ lnb,
    const float* __restrict__ wt2, const float* __restrict__ bt2,
    float* __restrict__ cwp1)
{
  const int b = blockIdx.x, t = threadIdx.x;
  __shared__ float pool[256];
  __shared__ float tt[32];
  pool[t] = pool_g[b * 256 + t];
  __syncthreads();
  if (t < 64) {
    float tv = 0.f;
    if (t < 32) {
      const float* wp = wt1 + (LL)t * 256;
      for (int c = 0; c < 256; ++c) tv = fmaf(wp[c], pool[c], tv);
      tv += bt1[t];
    }
    float s = tv;
#pragma unroll
    for (int k = 1; k <= 16; k <<= 1) s += __shfl_xor(s, k);
    float mu = s * (1.f / 32.f);
    float d = tv - mu;
    float vs = d * d;
#pragma unroll
    for (int k = 1; k <= 16; k <<= 1) vs += __shfl_xor(vs, k);
    float var = vs * (1.f / 32.f);
    if (t < 32) {
      float nrm = d / sqrtf(var + 1e-5f);
      float y = nrm * lng[t] + lnb[t];
      tt[t] = fmaxf(y, 0.f);
    }
  }
  __syncthreads();
  {
    float s2 = bt2[t];
    const float* wp = wt2 + (LL)t * 32;
#pragma unroll
    for (int i = 0; i < 32; ++i) s2 = fmaf(wp[i], tt[i], s2);
    cwp1[b * 256 + t] = 1.f + s2;
  }
}

// ======================================================================
// attn_stats: per (b,m) softmax max & inverse-sum over n=1024.
// ======================================================================
__global__ __launch_bounds__(256) void attn_stats(
    const unsigned short* __restrict__ qh_g, const unsigned short* __restrict__ ql_g,
    const unsigned short* __restrict__ kh_g, const unsigned short* __restrict__ kl_g,
    float* __restrict__ mxs, float* __restrict__ invl)
{
  const int t = threadIdx.x, w = t >> 6, lane = t & 63;
  const int lo4 = lane & 15, hi4 = lane >> 4;
  const int b = blockIdx.y, mc = blockIdx.x * 64;
  const float L2E = 1.4426950408889634f;

  short8 qh[4], ql[4];
#pragma unroll
  for (int mt = 0; mt < 4; ++mt) {
    const LL qa = ((LL)(b * 4096 + mc + mt * 16 + lo4)) * 32 + hi4 * 8;
    qh[mt] = *(const short8*)(qh_g + qa);
    ql[mt] = *(const short8*)(ql_g + qa);
  }

  float M[4], L[4];
#pragma unroll
  for (int mt = 0; mt < 4; ++mt) { M[mt] = -1e30f; L[mt] = 0.f; }

  for (int ns = 0; ns < 16; ++ns) {
    const int n = w * 256 + ns * 16 + lo4;
    const LL ka = ((LL)(b * 1024 + n)) * 32 + hi4 * 8;
    const short8 kh = *(const short8*)(kh_g + ka);
    const short8 kl = *(const short8*)(kl_g + ka);
#pragma unroll
    for (int mt = 0; mt < 4; ++mt) {
      f32x4 s = {0.f, 0.f, 0.f, 0.f};
      s = MFMA16(kl, qh[mt], s);
      s = MFMA16(kh, ql[mt], s);
      s = MFMA16(kh, qh[mt], s);
      float lm = fmaxf(fmaxf(s[0], s[1]), fmaxf(s[2], s[3]));
      float nM = fmaxf(M[mt], lm);
      float sc = exp2f((M[mt] - nM) * L2E);
      L[mt] = L[mt] * sc + exp2f((s[0] - nM) * L2E) + exp2f((s[1] - nM) * L2E)
                         + exp2f((s[2] - nM) * L2E) + exp2f((s[3] - nM) * L2E);
      M[mt] = nM;
    }
  }
#pragma unroll
  for (int mask = 16; mask <= 32; mask <<= 1) {
#pragma unroll
    for (int mt = 0; mt < 4; ++mt) {
      float oM = __shfl_xor(M[mt], mask), oL = __shfl_xor(L[mt], mask);
      float nM = fmaxf(M[mt], oM);
      L[mt] = L[mt] * exp2f((M[mt] - nM) * L2E) + oL * exp2f((oM - nM) * L2E);
      M[mt] = nM;
    }
  }
  __shared__ float sM[4][64], sL[4][64];
  if (lane < 16) {
#pragma unroll
    for (int mt = 0; mt < 4; ++mt) {
      sM[w][mt * 16 + lane] = M[mt];
      sL[w][mt * 16 + lane] = L[mt];
    }
  }
  __syncthreads();
  if (t < 64) {
    float Mg = sM[0][t], Lg = sL[0][t];
#pragma unroll
    for (int wv = 1; wv < 4; ++wv) {
      float oM = sM[wv][t], oL = sL[wv][t];
      float nM = fmaxf(Mg, oM);
      Lg = Lg * exp2f((Mg - nM) * L2E) + oL * exp2f((oM - nM) * L2E);
      Mg = nM;
    }
    mxs[b * 4096 + mc + t] = Mg * L2E;
    invl[b * 4096 + mc + t] = 1.f / Lg;
  }
}

// ======================================================================
// attn_pv: fused logits + softmax-apply + PV MFMA + epilogue.
// ======================================================================
__global__ __launch_bounds__(256) void attn_pv(
    const unsigned short* __restrict__ qh_g, const unsigned short* __restrict__ ql_g,
    const unsigned short* __restrict__ kh_g, const unsigned short* __restrict__ kl_g,
    const unsigned short* __restrict__ v16,
    const float* __restrict__ mxs, const float* __restrict__ invl,
    const float* __restrict__ x1, const float* __restrict__ cwp1,
    float* __restrict__ out)
{
  __shared__ __align__(16) unsigned short Pt[2][32][136];
  const int t = threadIdx.x, w = t >> 6, lane = t & 63;
  const int lo4 = lane & 15, hi4 = lane >> 4;
  const int b = blockIdx.y, mb = blockIdx.x * 32;
  const float L2E = 1.4426950408889634f;

  short8 qh[2], ql[2];
  float mxv[2], ilv[2];
#pragma unroll
  for (int mt = 0; mt < 2; ++mt) {
    const int m = mb + mt * 16 + lo4;
    const LL qa = ((LL)(b * 4096 + m)) * 32 + hi4 * 8;
    qh[mt] = *(const short8*)(qh_g + qa);
    ql[mt] = *(const short8*)(ql_g + qa);
    mxv[mt] = mxs[b * 4096 + m];
    ilv[mt] = invl[b * 4096 + m];
  }

  f32x4 acc[4][2];
#pragma unroll
  for (int ct = 0; ct < 4; ++ct)
#pragma unroll
    for (int mt = 0; mt < 2; ++mt) acc[ct][mt] = (f32x4){0.f, 0.f, 0.f, 0.f};

  // K fragments for nt=0
  short8 kh[2], kl[2];
#pragma unroll
  for (int ns = 0; ns < 2; ++ns) {
    const LL ka = ((LL)(b * 1024 + w * 32 + ns * 16 + lo4)) * 32 + hi4 * 8;
    kh[ns] = *(const short8*)(kh_g + ka);
    kl[ns] = *(const short8*)(kl_g + ka);
  }

  int buf = 0;
  for (int nt = 0; nt < 8; ++nt) {
    // prefetch next-nt K (wraps at 7; harmless dummy)
    short8 knh[2], knl[2];
    {
      const int ntn = (nt + 1) & 7;
#pragma unroll
      for (int ns = 0; ns < 2; ++ns) {
        const LL ka = ((LL)(b * 1024 + ntn * 128 + w * 32 + ns * 16 + lo4)) * 32 + hi4 * 8;
        knh[ns] = *(const short8*)(kh_g + ka);
        knl[ns] = *(const short8*)(kl_g + ka);
      }
    }
    // logits
    f32x4 s[2][2];
#pragma unroll
    for (int ns = 0; ns < 2; ++ns)
#pragma unroll
      for (int mt = 0; mt < 2; ++mt) {
        f32x4 z = {0.f, 0.f, 0.f, 0.f};
        z = MFMA16(kl[ns], qh[mt], z);
        z = MFMA16(kh[ns], ql[mt], z);
        z = MFMA16(kh[ns], qh[mt], z);
        s[ns][mt] = z;
      }
    // prefetch V for ks = 0,1 (independent of Pt)
    short8 vpre[2][4];
#pragma unroll
    for (int ks = 0; ks < 2; ++ks)
#pragma unroll
      for (int ct = 0; ct < 4; ++ct)
        vpre[ks][ct] = *(const short8*)(
            v16 + (((LL)b * 32 + nt * 4 + ks) * 256 + w * 64 + ct * 16 + lo4) * 32 + hi4 * 8);
    // softmax + pack + b64 LDS write
#pragma unroll
    for (int ns = 0; ns < 2; ++ns)
#pragma unroll
      for (int mt = 0; mt < 2; ++mt) {
        const int m_loc = mt * 16 + lo4;
        const int nl = w * 32 + ns * 16 + hi4 * 4;
        float p0 = exp2f(fmaf(s[ns][mt][0], L2E, -mxv[mt])) * ilv[mt];
        float p1 = exp2f(fmaf(s[ns][mt][1], L2E, -mxv[mt])) * ilv[mt];
        float p2 = exp2f(fmaf(s[ns][mt][2], L2E, -mxv[mt])) * ilv[mt];
        float p3 = exp2f(fmaf(s[ns][mt][3], L2E, -mxv[mt])) * ilv[mt];
        uint2v u;
        u[0] = (unsigned)f2bf(p0) | ((unsigned)f2bf(p1) << 16);
        u[1] = (unsigned)f2bf(p2) | ((unsigned)f2bf(p3) << 16);
        *(uint2v*)&Pt[buf][m_loc][nl] = u;
      }
    __syncthreads();
    // PV
#pragma unroll
    for (int ks = 0; ks < 4; ++ks) {
      short8 pb[2];
#pragma unroll
      for (int mt = 0; mt < 2; ++mt)
        pb[mt] = *(const short8*)&Pt[buf][mt * 16 + lo4][ks * 32 + hi4 * 8];
#pragma unroll
      for (int ct = 0; ct < 4; ++ct) {
        const short8 va = (ks < 2)
            ? vpre[ks][ct]
            : *(const short8*)(
                  v16 + (((LL)b * 32 + nt * 4 + ks) * 256 + w * 64 + ct * 16 + lo4) * 32 + hi4 * 8);
#pragma unroll
        for (int mt = 0; mt < 2; ++mt)
          acc[ct][mt] = MFMA16(va, pb[mt], acc[ct][mt]);
      }
    }
    buf ^= 1;
#pragma unroll
    for (int ns = 0; ns < 2; ++ns) { kh[ns] = knh[ns]; kl[ns] = knl[ns]; }
  }

#pragma unroll
  for (int ct = 0; ct < 4; ++ct)
#pragma unroll
    for (int mt = 0; mt < 2; ++mt) {
      const int m = mb + mt * 16 + lo4;
#pragma unroll
      for (int r = 0; r < 4; ++r) {
        const int c = w * 64 + ct * 16 + hi4 * 4 + r;
        const float cw = cwp1[b * 256 + c];
        const LL off = ((LL)(b * 256 + c)) * 4096 + m;
        out[off] = acc[ct][mt][r] + x1[off] * cw;
      }
    }
}

// ======================================================================
// launch
// ======================================================================
extern "C" void kernel_launch(void* const* d_in, const int* in_sizes, int n_in,
                              void* d_out, int out_size, void* d_ws, size_t ws_size,
                              hipStream_t stream) {
  const float* x1  = (const float*)d_in[0];
  const float* x2  = (const float*)d_in[1];
  const float* wq  = (const float*)d_in[2];
  const float* wk  = (const float*)d_in[3];
  const float* wv  = (const float*)d_in[4];
  const float* wc  = (const float*)d_in[5];
  const float* wch = (const float*)d_in[6];
  const float* wt1 = (const float*)d_in[7];
  const float* bt1 = (const float*)d_in[8];
  const float* lng = (const float*)d_in[9];
  const float* lnb = (const float*)d_in[10];
  const float* wt2 = (const float*)d_in[11];
  const float* bt2 = (const float*)d_in[12];
  float* outp = (float*)d_out;

  // ---- workspace (carve floats first, then shorts) ----
  float* ws   = (float*)d_ws;
  float* qtf  = ws;                      // q bf16 hi/lo region: 1,048,576 f
  float* ktf  = qtf + 1048576;           // k bf16 hi/lo region:   262,144 f
  float* mxsb = ktf + 262144;            //    32,768 f
  float* invb = mxsb + 32768;            //    32,768 f
  float* cfr  = invb + 32768;            //    32,768 f
  float* cfs  = cfr + 32768;             //    32,768 f
  float* Tb   = cfs + 32768;             //    18,432 f
  float* cwb  = Tb + 18432;              //     2,048 f
  unsigned short* sbase = (unsigned short*)(cwb + 2048);
  unsigned short* v16  = sbase;          // CHUNKED [8][32][256][32]  2,097,152 sh
  unsigned short* x1th = v16  + 2097152; // [8][8][4096][32]     8,388,608 sh
  unsigned short* x1tl = x1th + 8388608;
  unsigned short* x2th = x1tl + 8388608; // [8][16][1024][32]    4,194,304 sh
  unsigned short* x2tl = x2th + 4194304;
  unsigned short* wvt  = x2tl + 4194304; // [9][16][256][32]     1,179,648 sh
  unsigned short* wqh  = wvt  + 1179648; // [9][8][32][32]          73,728 sh
  unsigned short* wql  = wqh  + 73728;
  unsigned short* wkh  = wql  + 73728;   // [9][16][32][32]        147,456 sh
  unsigned short* wkl  = wkh  + 147456;

  // bf16 hi/lo attn operands (alias the fp32 regions exactly):
  unsigned short* qhg = (unsigned short*)qtf;   // [8][4096][32] sh
  unsigned short* qlg = qhg + 1048576;
  unsigned short* khg = (unsigned short*)ktf;   // [8][1024][32] sh
  unsigned short* klg = khg + 262144;

  // zero only the atomic-accumulated T buffer
  hipMemsetAsync(Tb, 0, (size_t)18432 * 4, stream);

  // weight pre-transforms ([9][IC/32][OC][32])
  wtrans2<<<dim3(4608), 256, 0, stream>>>(wv, wvt, nullptr, 256, 512);
  wtrans2<<<dim3(288),  256, 0, stream>>>(wq, wqh, wql, 32, 256);
  wtrans2<<<dim3(576),  256, 0, stream>>>(wk, wkh, wkl, 32, 512);

  // input transposes: [b][c][n] fp32 -> chunked [b][c/32][n][32] bf16 hi/lo
  transp<<<dim3(64, 4, 8), 256, 0, stream>>>(x1, x1th, x1tl, 256, 4096);
  transp<<<dim3(16, 8, 8), 256, 0, stream>>>(x2, x2th, x2tl, 512, 1024);

  // k conv (x2, C=512): 16 waves, full in-block K-split, direct bf16 out
  conv_qk_s<16><<<dim3(32, 1, 8), 1024, 0, stream>>>(
      x2th, x2tl, wkh, wkl, khg, klg, 5, 32);

  // v conv (x2): 8 waves = 2 rows x 4 K-parts, direct bf16 out
  conv_v_s<<<dim3(16, 8, 8), 512, 0, stream>>>(x2th, wvt, v16);

  // q conv (x1, C=256): 8 waves, full in-block K-split, direct bf16 out
  conv_qk_s<8><<<dim3(128, 1, 8), 512, 0, stream>>>(
      x1th, x1tl, wqh, wql, qhg, qlg, 6, 64);

  // channel branch
  cf_dot<<<dim3(16, 8), 256, 0, stream>>>(x1, wc, cfr);
  cf_softmax<<<dim3(8), 1024, 0, stream>>>(cfr, cfs);
  ykern<<<dim3(16, 8), 256, 0, stream>>>(x1, cfs, Tb);
  pool_k<<<dim3(32, 8), 256, 0, stream>>>(Tb, wch, cfr);
  chw_tail<<<dim3(8), 256, 0, stream>>>(cfr, wt1, bt1, lng, lnb, wt2, bt2, cwb);

  // attention
  attn_stats<<<dim3(64, 8), 256, 0, stream>>>(qhg, qlg, khg, klg, mxsb, invb);
  attn_pv<<<dim3(128, 8), 256, 0, stream>>>(qhg, qlg, khg, klg, v16, mxsb, invb, x1, cwb, outp);
}

// Round 8
// 417.902 us; speedup vs baseline: 1.0717x; 1.0234x over previous
//
#include <hip/hip_runtime.h>
#include <stdint.h>

#define LL long long

typedef short short8 __attribute__((ext_vector_type(8)));
typedef float f32x4 __attribute__((ext_vector_type(4)));
typedef unsigned int uint2v __attribute__((ext_vector_type(2)));

__device__ __forceinline__ unsigned short f2bf(float f) {
  unsigned u = __float_as_uint(f);
  unsigned r = (u + 0x7fffu + ((u >> 16) & 1u)) >> 16;
  return (unsigned short)r;
}
__device__ __forceinline__ float bf2f(unsigned short h) {
  return __uint_as_float(((unsigned)h) << 16);
}

#define MFMA16(A, B, C) __builtin_amdgcn_mfma_f32_16x16x32_bf16(A, B, C, 0, 0, 0)

// ======================================================================
// Weight pre-transform: src fp32 [OC][IC][3][3] -> bf16 [9][IC/32][OC][32]
// ======================================================================
__global__ __launch_bounds__(256) void wtrans2(
    const float* __restrict__ src, unsigned short* __restrict__ dh,
    unsigned short* __restrict__ dl, int OC, int IC)
{
  const int i = blockIdx.x * 256 + threadIdx.x;
  if (i >= OC * IC * 9) return;
  const int off = i % 9;
  const int rest = i / 9;
  const int ic = rest % IC;
  const int oc = rest / IC;
  const float v = src[i];
  const unsigned short h = f2bf(v);
  const LL di = (((LL)off * (IC >> 5) + (ic >> 5)) * OC + oc) * 32 + (ic & 31);
  dh[di] = h;
  if (dl) dl[di] = f2bf(v - bf2f(h));
}

// ======================================================================
// transp: src fp32 [B][C][N] -> dh/dl bf16 CHUNKED [B][C/32][N][32]
// ======================================================================
__global__ __launch_bounds__(256) void transp(
    const float* __restrict__ src, unsigned short* __restrict__ dh,
    unsigned short* __restrict__ dl, int C, int N)
{
  __shared__ unsigned short sh[64 * 66];
  __shared__ unsigned short sl[64 * 66];
  const int t = threadIdx.x;
  const int b = blockIdx.z;
  const int n0 = blockIdx.x * 64, c0 = blockIdx.y * 64;
  {
    const int nl = t & 63, cl0 = t >> 6;
#pragma unroll
    for (int i = 0; i < 16; ++i) {
      const int cl = cl0 + 4 * i;
      const float v = src[((LL)b * C + c0 + cl) * N + n0 + nl];
      const unsigned short h = f2bf(v);
      sh[nl * 66 + cl] = h;
      sl[nl * 66 + cl] = f2bf(v - bf2f(h));
    }
  }
  __syncthreads();
  {
    const int cl = t & 63, nr0 = t >> 6;
    const int chunk = (c0 + cl) >> 5;   // c0 is a multiple of 64
    const int cin = cl & 31;
#pragma unroll
    for (int j = 0; j < 16; ++j) {
      const int nr = nr0 + 4 * j;
      const LL di = (((LL)b * (C >> 5) + chunk) * N + n0 + nr) * 32 + cin;
      dh[di] = sh[nr * 66 + cl];
      if (dl) dl[di] = sl[nr * 66 + cl];
    }
  }
}

// ======================================================================
// conv_qk_s<NW>: in-block FULL K-split 3x3 conv, bf16x2, NW waves,
// one 32-ch chunk per wave (C = NW*32). LDS all-wave reduction, then
// bf16 hi/lo split written DIRECTLY. q: NW=8, k: NW=16.
// ======================================================================
template<int NW>
__global__ __launch_bounds__(NW * 64) void conv_qk_s(
    const unsigned short* __restrict__ xh, const unsigned short* __restrict__ xl,
    const unsigned short* __restrict__ wh, const unsigned short* __restrict__ wl,
    unsigned short* __restrict__ dh, unsigned short* __restrict__ dl,
    int logW, int H)
{
  __shared__ float sred[NW][16][64];
  const int t = threadIdx.x, w = t >> 6, lane = t & 63;
  const int lo4 = lane & 15, hi4 = lane >> 4;
  const int b = blockIdx.z;
  const int W = 1 << logW;
  const int N = H * W;
  const int px0 = blockIdx.x * 32;
  const int row = px0 >> logW;       // wave-uniform (32 px within one row)
  const int x0 = px0 & (W - 1);
  const int ch = w;                  // one chunk per wave
  const short8 zero8 = {0, 0, 0, 0, 0, 0, 0, 0};

  f32x4 acc[2][2];
#pragma unroll
  for (int p = 0; p < 2; ++p)
#pragma unroll
    for (int ot = 0; ot < 2; ++ot) acc[p][ot] = (f32x4){0.f, 0.f, 0.f, 0.f};

  const LL xbase = ((LL)(b * NW + ch)) * N * 32 + hi4 * 8;
#pragma unroll
  for (int ky = 0; ky < 3; ++ky) {
    const int gy = row + ky - 1;
    const bool oky = (unsigned)gy < (unsigned)H;
    const int gyc = min(max(gy, 0), H - 1);
#pragma unroll
    for (int kx = 0; kx < 3; ++kx) {
      short8 Bh[2], Bl[2];
#pragma unroll
      for (int p = 0; p < 2; ++p) {
        const int gx = x0 + p * 16 + lo4 + kx - 1;
        const bool ok = oky && ((unsigned)gx < (unsigned)W);
        const int gxc = min(max(gx, 0), W - 1);
        const LL xoff = xbase + (LL)(gyc * W + gxc) * 32;
        const short8 bh = *(const short8*)(xh + xoff);
        const short8 bl = *(const short8*)(xl + xoff);
        Bh[p] = ok ? bh : zero8;
        Bl[p] = ok ? bl : zero8;
      }
      const int off = ky * 3 + kx;
      short8 Ah[2], Al[2];
#pragma unroll
      for (int ot = 0; ot < 2; ++ot) {
        const LL wi = ((LL)(off * NW + ch) * 32 + ot * 16 + lo4) * 32 + hi4 * 8;
        Ah[ot] = *(const short8*)(wh + wi);
        Al[ot] = *(const short8*)(wl + wi);
      }
#pragma unroll
      for (int p = 0; p < 2; ++p)
#pragma unroll
        for (int ot = 0; ot < 2; ++ot) {
          acc[p][ot] = MFMA16(Ah[ot], Bh[p], acc[p][ot]);
          acc[p][ot] = MFMA16(Ah[ot], Bl[p], acc[p][ot]);
          acc[p][ot] = MFMA16(Al[ot], Bh[p], acc[p][ot]);
        }
    }
  }
  // dump all partials to LDS
#pragma unroll
  for (int p = 0; p < 2; ++p)
#pragma unroll
    for (int ot = 0; ot < 2; ++ot)
#pragma unroll
      for (int r = 0; r < 4; ++r)
        sred[w][p * 8 + ot * 4 + r][lane] = acc[p][ot][r];
  __syncthreads();
  // each wave reduces 16/NW slots and writes bf16 hi/lo directly
  constexpr int SPW = 16 / NW;
#pragma unroll
  for (int si = 0; si < SPW; ++si) {
    const int slot = w * SPW + si;
    float v = sred[0][slot][lane];
#pragma unroll
    for (int j = 1; j < NW; ++j) v += sred[j][slot][lane];
    const int p = slot >> 3, ot = (slot >> 2) & 1, r = slot & 3;
    const LL di = ((LL)b * N + px0 + p * 16 + lo4) * 32 + ot * 16 + hi4 * 4 + r;
    const unsigned short h = f2bf(v);
    dh[di] = h;
    dl[di] = f2bf(v - bf2f(h));
  }
}

// ======================================================================
// conv_v_w: row-reuse register-tiled conv. Wave = 4 output rows x 16 px
// x 32 oc, acc[4][2]. A[9][2] staged in regs per ch; 6-row gy sweep
// loads each B fragment ONCE (3 kx shifts) -> 0.5 loads/MFMA (vs 1.0).
// 8 waves = 2 px-halves x 2 oc-groups x 2 K-parts; LDS pair-reduction.
// Output CHUNKED v16 [b][row=32][oc=256][32px].
// ======================================================================
__global__ __launch_bounds__(512) void conv_v_w(
    const unsigned short* __restrict__ xh, const unsigned short* __restrict__ wt,
    unsigned short* __restrict__ out)
{
  __shared__ float sred[4][32][64];
  const int t = threadIdx.x, w = t >> 6, lane = t & 63;
  const int lo4 = lane & 15, hi4 = lane >> 4;
  const int b = blockIdx.z;
  const int h = w & 1, ocg = (w >> 1) & 1, kp = w >> 2;
  const int r0 = blockIdx.x * 4;                      // output rows r0..r0+3
  const int ocb = blockIdx.y * 64 + ocg * 32;         // wave oc base
  const short8 zero8 = {0, 0, 0, 0, 0, 0, 0, 0};

  f32x4 acc[4][2];
#pragma unroll
  for (int rr = 0; rr < 4; ++rr)
#pragma unroll
    for (int ot = 0; ot < 2; ++ot) acc[rr][ot] = (f32x4){0.f, 0.f, 0.f, 0.f};

  for (int ch = kp * 8; ch < kp * 8 + 8; ++ch) {
    // stage all A fragments for this ch: [ky][kx][ot]
    short8 A[3][3][2];
#pragma unroll
    for (int ky = 0; ky < 3; ++ky)
#pragma unroll
      for (int kx = 0; kx < 3; ++kx)
#pragma unroll
        for (int ot = 0; ot < 2; ++ot) {
          const int off = ky * 3 + kx;
          A[ky][kx][ot] = *(const short8*)(
              wt + ((LL)(off * 16 + ch) * 256 + ocb + ot * 16 + lo4) * 32 + hi4 * 8);
        }
    const LL xchb = ((LL)(b * 16 + ch)) * 1024 * 32 + hi4 * 8;
    // sweep 6 input rows; each B fragment loaded once, reused across ky
#pragma unroll
    for (int g = 0; g < 6; ++g) {
      const int gy = r0 - 1 + g;
      const bool oky = (unsigned)gy < 32u;
      const int gyc = min(max(gy, 0), 31);
      short8 Bg[3];
#pragma unroll
      for (int kx = 0; kx < 3; ++kx) {
        const int gx = h * 16 + lo4 + kx - 1;
        const bool ok = oky && ((unsigned)gx < 32u);
        const int gxc = min(max(gx, 0), 31);
        const short8 bv = *(const short8*)(xh + xchb + (LL)(gyc * 32 + gxc) * 32);
        Bg[kx] = ok ? bv : zero8;
      }
#pragma unroll
      for (int rr = 0; rr < 4; ++rr) {
        if (rr > g || rr + 2 < g) continue;   // compile-time (g, rr unrolled)
        const int ky = g - rr;
#pragma unroll
        for (int kx = 0; kx < 3; ++kx)
#pragma unroll
          for (int ot = 0; ot < 2; ++ot)
            acc[rr][ot] = MFMA16(A[ky][kx][ot], Bg[kx], acc[rr][ot]);
      }
    }
  }
  // pair-reduce kp=1 into kp=0, write bf16 chunked output
  const int slotbase = h * 2 + ocg;   // 4 (h,ocg) groups
  if (kp == 1) {
#pragma unroll
    for (int rr = 0; rr < 4; ++rr)
#pragma unroll
      for (int ot = 0; ot < 2; ++ot)
#pragma unroll
        for (int r = 0; r < 4; ++r)
          sred[slotbase][rr * 8 + ot * 4 + r][lane] = acc[rr][ot][r];
  }
  __syncthreads();
  if (kp == 0) {
#pragma unroll
    for (int rr = 0; rr < 4; ++rr)
#pragma unroll
      for (int ot = 0; ot < 2; ++ot)
#pragma unroll
        for (int r = 0; r < 4; ++r) {
          const float v = acc[rr][ot][r] + sred[slotbase][rr * 8 + ot * 4 + r][lane];
          const int row = r0 + rr;
          const int oc = ocb + ot * 16 + hi4 * 4 + r;
          out[(((LL)b * 32 + row) * 256 + oc) * 32 + h * 16 + lo4] = f2bf(v);
        }
  }
}

// ======================================================================
// cf[b][n] = sum_c x1[b][c][n] * wc[c]
// ======================================================================
__global__ __launch_bounds__(256) void cf_dot(
    const float* __restrict__ x1, const float* __restrict__ wc, float* __restrict__ cf)
{
  const int b = blockIdx.y;
  const int n = blockIdx.x * 256 + threadIdx.x;
  const float* xp = x1 + (LL)b * 256 * 4096 + n;
  float a = 0.f;
#pragma unroll 4
  for (int c = 0; c < 256; ++c)
    a = fmaf(xp[(LL)c * 4096], wc[c], a);
  cf[b * 4096 + n] = a;
}

// ======================================================================
// softmax over 4096 per batch
// ======================================================================
__global__ __launch_bounds__(1024) void cf_softmax(
    const float* __restrict__ cf, float* __restrict__ cfs)
{
  const int b = blockIdx.x, t = threadIdx.x;
  __shared__ float r1[16];
  __shared__ float r2[16];
  float v[4];
#pragma unroll
  for (int j = 0; j < 4; ++j) v[j] = cf[b * 4096 + t + 1024 * j];
  float mx = fmaxf(fmaxf(v[0], v[1]), fmaxf(v[2], v[3]));
#pragma unroll
  for (int k = 1; k <= 32; k <<= 1) mx = fmaxf(mx, __shfl_xor(mx, k));
  const int wv = t >> 6;
  if ((t & 63) == 0) r1[wv] = mx;
  __syncthreads();
  float m2 = r1[0];
#pragma unroll
  for (int i = 1; i < 16; ++i) m2 = fmaxf(m2, r1[i]);
  float e[4]; float s = 0.f;
#pragma unroll
  for (int j = 0; j < 4; ++j) { e[j] = __expf(v[j] - m2); s += e[j]; }
#pragma unroll
  for (int k = 1; k <= 32; k <<= 1) s += __shfl_xor(s, k);
  if ((t & 63) == 0) r2[wv] = s;
  __syncthreads();
  float s2 = 0.f;
#pragma unroll
  for (int i = 0; i < 16; ++i) s2 += r2[i];
  const float inv = 1.f / s2;
#pragma unroll
  for (int j = 0; j < 4; ++j) cfs[b * 4096 + t + 1024 * j] = e[j] * inv;
}

// ======================================================================
// T[b][c][dy*3+dx] = sum_{y,x} x1[b][c][y][x] * cfs[b][y+1-dy][x+1-dx]
// ======================================================================
__global__ __launch_bounds__(256) void ykern(
    const float* __restrict__ x1, const float* __restrict__ cfs, float* __restrict__ T)
{
  __shared__ float cl[6][64];
  const int chunk = blockIdx.x, b = blockIdx.y, t = threadIdx.x;
  for (int idx = t; idx < 384; idx += 256) {
    int lr = idx >> 6, col = idx & 63;
    int gr = chunk * 4 - 1 + lr;
    cl[lr][col] = ((unsigned)gr < 64u) ? cfs[b * 4096 + gr * 64 + col] : 0.f;
  }
  __syncthreads();
  const int c = t;
  float a[9];
#pragma unroll
  for (int k = 0; k < 9; ++k) a[k] = 0.f;
  const float* xp = x1 + ((LL)b * 256 + c) * 4096 + chunk * 256;
  for (int i = 0; i < 256; ++i) {
    float xv = xp[i];
    int yl = i >> 6, col = i & 63;
#pragma unroll
    for (int dy = 0; dy < 3; ++dy) {
      int lr = yl + 2 - dy;
#pragma unroll
      for (int dx = 0; dx < 3; ++dx) {
        int cc = col + 1 - dx;
        float f = ((unsigned)cc < 64u) ? cl[lr][cc] : 0.f;
        a[dy * 3 + dx] = fmaf(xv, f, a[dy * 3 + dx]);
      }
    }
  }
#pragma unroll
  for (int k = 0; k < 9; ++k)
    atomicAdd(&T[((LL)b * 256 + c) * 9 + k], a[k]);
}

// ======================================================================
// pool_k: pool[b][oc] = wch[oc][:] . T[b][:]  (2304-dot)
// ======================================================================
__global__ __launch_bounds__(256) void pool_k(
    const float* __restrict__ T, const float* __restrict__ wch,
    float* __restrict__ pool)
{
  __shared__ __align__(16) float Tl[2304];
  const int b = blockIdx.y, ocg = blockIdx.x;
  const int t = threadIdx.x, w = t >> 6, lane = t & 63;
  for (int i = t; i < 2304; i += 256) Tl[i] = T[(LL)b * 2304 + i];
  __syncthreads();
  const float4* tp = (const float4*)Tl;
#pragma unroll
  for (int oi = 0; oi < 2; ++oi) {
    const int oc = ocg * 8 + w * 2 + oi;
    const float4* wp = (const float4*)(wch + (LL)oc * 2304);
    float a = 0.f;
#pragma unroll
    for (int j = 0; j < 9; ++j) {
      const int idx = lane + 64 * j;
      float4 w4 = wp[idx], t4 = tp[idx];
      a = fmaf(w4.x, t4.x, a); a = fmaf(w4.y, t4.y, a);
      a = fmaf(w4.z, t4.z, a); a = fmaf(w4.w, t4.w, a);
    }
#pragma unroll
    for (int k = 1; k <= 32; k <<= 1) a += __shfl_xor(a, k);
    if (lane == 0) pool[b * 256 + oc] = a;
  }
}

// ======================================================================
// chw_tail: t1 = wt1.pool + bt1 ; LN(32) ; relu ; cwp1 = 1 + wt2.t + bt2
// ======================================================================
__global__ __launch_bounds__(256) void chw_tail(
    const float* __restrict__ pool_g,
    const float* __restrict__ wt1, const float* __restrict__ bt1,
    const float* __restrict__ lng, const float* __restrict__ lnb,
    const float* __restrict__ wt2, const float* __restrict__ bt2,
    float* __restrict__ cwp1)
{
  const int b = blockIdx.x, t = threadIdx.x;
  __shared__ float pool[256];
  __shared__ float tt[32];
  pool[t] = pool_g[b * 256 + t];
  __syncthreads();
  if (t < 64) {
    float tv = 0.f;
    if (t < 32) {
      const float* wp = wt1 + (LL)t * 256;
      for (int c = 0; c < 256; ++c) tv = fmaf(wp[c], pool[c], tv);
      tv += bt1[t];
    }
    float s = tv;
#pragma unroll
    for (int k = 1; k <= 16; k <<= 1) s += __shfl_xor(s, k);
    float mu = s * (1.f / 32.f);
    float d = tv - mu;
    float vs = d * d;
#pragma unroll
    for (int k = 1; k <= 16; k <<= 1) vs += __shfl_xor(vs, k);
    float var = vs * (1.f / 32.f);
    if (t < 32) {
      float nrm = d / sqrtf(var + 1e-5f);
      float y = nrm * lng[t] + lnb[t];
      tt[t] = fmaxf(y, 0.f);
    }
  }
  __syncthreads();
  {
    float s2 = bt2[t];
    const float* wp = wt2 + (LL)t * 32;
#pragma unroll
    for (int i = 0; i < 32; ++i) s2 = fmaf(wp[i], tt[i], s2);
    cwp1[b * 256 + t] = 1.f + s2;
  }
}

// ======================================================================
// attn_stats: per (b,m) softmax max & inverse-sum over n=1024.
// ======================================================================
__global__ __launch_bounds__(256) void attn_stats(
    const unsigned short* __restrict__ qh_g, const unsigned short* __restrict__ ql_g,
    const unsigned short* __restrict__ kh_g, const unsigned short* __restrict__ kl_g,
    float* __restrict__ mxs, float* __restrict__ invl)
{
  const int t = threadIdx.x, w = t >> 6, lane = t & 63;
  const int lo4 = lane & 15, hi4 = lane >> 4;
  const int b = blockIdx.y, mc = blockIdx.x * 64;
  const float L2E = 1.4426950408889634f;

  short8 qh[4], ql[4];
#pragma unroll
  for (int mt = 0; mt < 4; ++mt) {
    const LL qa = ((LL)(b * 4096 + mc + mt * 16 + lo4)) * 32 + hi4 * 8;
    qh[mt] = *(const short8*)(qh_g + qa);
    ql[mt] = *(const short8*)(ql_g + qa);
  }

  float M[4], L[4];
#pragma unroll
  for (int mt = 0; mt < 4; ++mt) { M[mt] = -1e30f; L[mt] = 0.f; }

  for (int ns = 0; ns < 16; ++ns) {
    const int n = w * 256 + ns * 16 + lo4;
    const LL ka = ((LL)(b * 1024 + n)) * 32 + hi4 * 8;
    const short8 kh = *(const short8*)(kh_g + ka);
    const short8 kl = *(const short8*)(kl_g + ka);
#pragma unroll
    for (int mt = 0; mt < 4; ++mt) {
      f32x4 s = {0.f, 0.f, 0.f, 0.f};
      s = MFMA16(kl, qh[mt], s);
      s = MFMA16(kh, ql[mt], s);
      s = MFMA16(kh, qh[mt], s);
      float lm = fmaxf(fmaxf(s[0], s[1]), fmaxf(s[2], s[3]));
      float nM = fmaxf(M[mt], lm);
      float sc = exp2f((M[mt] - nM) * L2E);
      L[mt] = L[mt] * sc + exp2f((s[0] - nM) * L2E) + exp2f((s[1] - nM) * L2E)
                         + exp2f((s[2] - nM) * L2E) + exp2f((s[3] - nM) * L2E);
      M[mt] = nM;
    }
  }
#pragma unroll
  for (int mask = 16; mask <= 32; mask <<= 1) {
#pragma unroll
    for (int mt = 0; mt < 4; ++mt) {
      float oM = __shfl_xor(M[mt], mask), oL = __shfl_xor(L[mt], mask);
      float nM = fmaxf(M[mt], oM);
      L[mt] = L[mt] * exp2f((M[mt] - nM) * L2E) + oL * exp2f((oM - nM) * L2E);
      M[mt] = nM;
    }
  }
  __shared__ float sM[4][64], sL[4][64];
  if (lane < 16) {
#pragma unroll
    for (int mt = 0; mt < 4; ++mt) {
      sM[w][mt * 16 + lane] = M[mt];
      sL[w][mt * 16 + lane] = L[mt];
    }
  }
  __syncthreads();
  if (t < 64) {
    float Mg = sM[0][t], Lg = sL[0][t];
#pragma unroll
    for (int wv = 1; wv < 4; ++wv) {
      float oM = sM[wv][t], oL = sL[wv][t];
      float nM = fmaxf(Mg, oM);
      Lg = Lg * exp2f((Mg - nM) * L2E) + oL * exp2f((oM - nM) * L2E);
      Mg = nM;
    }
    mxs[b * 4096 + mc + t] = Mg * L2E;
    invl[b * 4096 + mc + t] = 1.f / Lg;
  }
}

// ======================================================================
// attn_pv: fused logits + softmax-apply + PV MFMA + epilogue.
// ======================================================================
__global__ __launch_bounds__(256) void attn_pv(
    const unsigned short* __restrict__ qh_g, const unsigned short* __restrict__ ql_g,
    const unsigned short* __restrict__ kh_g, const unsigned short* __restrict__ kl_g,
    const unsigned short* __restrict__ v16,
    const float* __restrict__ mxs, const float* __restrict__ invl,
    const float* __restrict__ x1, const float* __restrict__ cwp1,
    float* __restrict__ out)
{
  __shared__ __align__(16) unsigned short Pt[2][32][136];
  const int t = threadIdx.x, w = t >> 6, lane = t & 63;
  const int lo4 = lane & 15, hi4 = lane >> 4;
  const int b = blockIdx.y, mb = blockIdx.x * 32;
  const float L2E = 1.4426950408889634f;

  short8 qh[2], ql[2];
  float mxv[2], ilv[2];
#pragma unroll
  for (int mt = 0; mt < 2; ++mt) {
    const int m = mb + mt * 16 + lo4;
    const LL qa = ((LL)(b * 4096 + m)) * 32 + hi4 * 8;
    qh[mt] = *(const short8*)(qh_g + qa);
    ql[mt] = *(const short8*)(ql_g + qa);
    mxv[mt] = mxs[b * 4096 + m];
    ilv[mt] = invl[b * 4096 + m];
  }

  f32x4 acc[4][2];
#pragma unroll
  for (int ct = 0; ct < 4; ++ct)
#pragma unroll
    for (int mt = 0; mt < 2; ++mt) acc[ct][mt] = (f32x4){0.f, 0.f, 0.f, 0.f};

  // K fragments for nt=0
  short8 kh[2], kl[2];
#pragma unroll
  for (int ns = 0; ns < 2; ++ns) {
    const LL ka = ((LL)(b * 1024 + w * 32 + ns * 16 + lo4)) * 32 + hi4 * 8;
    kh[ns] = *(const short8*)(kh_g + ka);
    kl[ns] = *(const short8*)(kl_g + ka);
  }

  int buf = 0;
  for (int nt = 0; nt < 8; ++nt) {
    // prefetch next-nt K (wraps at 7; harmless dummy)
    short8 knh[2], knl[2];
    {
      const int ntn = (nt + 1) & 7;
#pragma unroll
      for (int ns = 0; ns < 2; ++ns) {
        const LL ka = ((LL)(b * 1024 + ntn * 128 + w * 32 + ns * 16 + lo4)) * 32 + hi4 * 8;
        knh[ns] = *(const short8*)(kh_g + ka);
        knl[ns] = *(const short8*)(kl_g + ka);
      }
    }
    // logits
    f32x4 s[2][2];
#pragma unroll
    for (int ns = 0; ns < 2; ++ns)
#pragma unroll
      for (int mt = 0; mt < 2; ++mt) {
        f32x4 z = {0.f, 0.f, 0.f, 0.f};
        z = MFMA16(kl[ns], qh[mt], z);
        z = MFMA16(kh[ns], ql[mt], z);
        z = MFMA16(kh[ns], qh[mt], z);
        s[ns][mt] = z;
      }
    // prefetch V for ks = 0,1 (independent of Pt)
    short8 vpre[2][4];
#pragma unroll
    for (int ks = 0; ks < 2; ++ks)
#pragma unroll
      for (int ct = 0; ct < 4; ++ct)
        vpre[ks][ct] = *(const short8*)(
            v16 + (((LL)b * 32 + nt * 4 + ks) * 256 + w * 64 + ct * 16 + lo4) * 32 + hi4 * 8);
    // softmax + pack + b64 LDS write
#pragma unroll
    for (int ns = 0; ns < 2; ++ns)
#pragma unroll
      for (int mt = 0; mt < 2; ++mt) {
        const int m_loc = mt * 16 + lo4;
        const int nl = w * 32 + ns * 16 + hi4 * 4;
        float p0 = exp2f(fmaf(s[ns][mt][0], L2E, -mxv[mt])) * ilv[mt];
        float p1 = exp2f(fmaf(s[ns][mt][1], L2E, -mxv[mt])) * ilv[mt];
        float p2 = exp2f(fmaf(s[ns][mt][2], L2E, -mxv[mt])) * ilv[mt];
        float p3 = exp2f(fmaf(s[ns][mt][3], L2E, -mxv[mt])) * ilv[mt];
        uint2v u;
        u[0] = (unsigned)f2bf(p0) | ((unsigned)f2bf(p1) << 16);
        u[1] = (unsigned)f2bf(p2) | ((unsigned)f2bf(p3) << 16);
        *(uint2v*)&Pt[buf][m_loc][nl] = u;
      }
    __syncthreads();
    // PV
#pragma unroll
    for (int ks = 0; ks < 4; ++ks) {
      short8 pb[2];
#pragma unroll
      for (int mt = 0; mt < 2; ++mt)
        pb[mt] = *(const short8*)&Pt[buf][mt * 16 + lo4][ks * 32 + hi4 * 8];
#pragma unroll
      for (int ct = 0; ct < 4; ++ct) {
        const short8 va = (ks < 2)
            ? vpre[ks][ct]
            : *(const short8*)(
                  v16 + (((LL)b * 32 + nt * 4 + ks) * 256 + w * 64 + ct * 16 + lo4) * 32 + hi4 * 8);
#pragma unroll
        for (int mt = 0; mt < 2; ++mt)
          acc[ct][mt] = MFMA16(va, pb[mt], acc[ct][mt]);
      }
    }
    buf ^= 1;
#pragma unroll
    for (int ns = 0; ns < 2; ++ns) { kh[ns] = knh[ns]; kl[ns] = knl[ns]; }
  }

#pragma unroll
  for (int ct = 0; ct < 4; ++ct)
#pragma unroll
    for (int mt = 0; mt < 2; ++mt) {
      const int m = mb + mt * 16 + lo4;
#pragma unroll
      for (int r = 0; r < 4; ++r) {
        const int c = w * 64 + ct * 16 + hi4 * 4 + r;
        const float cw = cwp1[b * 256 + c];
        const LL off = ((LL)(b * 256 + c)) * 4096 + m;
        out[off] = acc[ct][mt][r] + x1[off] * cw;
      }
    }
}

// ======================================================================
// launch
// ======================================================================
extern "C" void kernel_launch(void* const* d_in, const int* in_sizes, int n_in,
                              void* d_out, int out_size, void* d_ws, size_t ws_size,
                              hipStream_t stream) {
  const float* x1  = (const float*)d_in[0];
  const float* x2  = (const float*)d_in[1];
  const float* wq  = (const float*)d_in[2];
  const float* wk  = (const float*)d_in[3];
  const float* wv  = (const float*)d_in[4];
  const float* wc  = (const float*)d_in[5];
  const float* wch = (const float*)d_in[6];
  const float* wt1 = (const float*)d_in[7];
  const float* bt1 = (const float*)d_in[8];
  const float* lng = (const float*)d_in[9];
  const float* lnb = (const float*)d_in[10];
  const float* wt2 = (const float*)d_in[11];
  const float* bt2 = (const float*)d_in[12];
  float* outp = (float*)d_out;

  // ---- workspace (carve floats first, then shorts) ----
  float* ws   = (float*)d_ws;
  float* qtf  = ws;                      // q bf16 hi/lo region: 1,048,576 f
  float* ktf  = qtf + 1048576;           // k bf16 hi/lo region:   262,144 f
  float* mxsb = ktf + 262144;            //    32,768 f
  float* invb = mxsb + 32768;            //    32,768 f
  float* cfr  = invb + 32768;            //    32,768 f
  float* cfs  = cfr + 32768;             //    32,768 f
  float* Tb   = cfs + 32768;             //    18,432 f
  float* cwb  = Tb + 18432;              //     2,048 f
  unsigned short* sbase = (unsigned short*)(cwb + 2048);
  unsigned short* v16  = sbase;          // CHUNKED [8][32][256][32]  2,097,152 sh
  unsigned short* x1th = v16  + 2097152; // [8][8][4096][32]     8,388,608 sh
  unsigned short* x1tl = x1th + 8388608;
  unsigned short* x2th = x1tl + 8388608; // [8][16][1024][32]    4,194,304 sh
  unsigned short* x2tl = x2th + 4194304;
  unsigned short* wvt  = x2tl + 4194304; // [9][16][256][32]     1,179,648 sh
  unsigned short* wqh  = wvt  + 1179648; // [9][8][32][32]          73,728 sh
  unsigned short* wql  = wqh  + 73728;
  unsigned short* wkh  = wql  + 73728;   // [9][16][32][32]        147,456 sh
  unsigned short* wkl  = wkh  + 147456;

  // bf16 hi/lo attn operands (alias the fp32 regions exactly):
  unsigned short* qhg = (unsigned short*)qtf;   // [8][4096][32] sh
  unsigned short* qlg = qhg + 1048576;
  unsigned short* khg = (unsigned short*)ktf;   // [8][1024][32] sh
  unsigned short* klg = khg + 262144;

  // zero only the atomic-accumulated T buffer
  hipMemsetAsync(Tb, 0, (size_t)18432 * 4, stream);

  // weight pre-transforms ([9][IC/32][OC][32])
  wtrans2<<<dim3(4608), 256, 0, stream>>>(wv, wvt, nullptr, 256, 512);
  wtrans2<<<dim3(288),  256, 0, stream>>>(wq, wqh, wql, 32, 256);
  wtrans2<<<dim3(576),  256, 0, stream>>>(wk, wkh, wkl, 32, 512);

  // input transposes: [b][c][n] fp32 -> chunked [b][c/32][n][32] bf16 hi/lo
  transp<<<dim3(64, 4, 8), 256, 0, stream>>>(x1, x1th, x1tl, 256, 4096);
  transp<<<dim3(16, 8, 8), 256, 0, stream>>>(x2, x2th, x2tl, 512, 1024);

  // k conv (x2, C=512): 16 waves, full in-block K-split, direct bf16 out
  conv_qk_s<16><<<dim3(32, 1, 8), 1024, 0, stream>>>(
      x2th, x2tl, wkh, wkl, khg, klg, 5, 32);

  // v conv (x2): row-reuse register-tiled, 0.5 loads/MFMA
  conv_v_w<<<dim3(8, 4, 8), 512, 0, stream>>>(x2th, wvt, v16);

  // q conv (x1, C=256): 8 waves, full in-block K-split, direct bf16 out
  conv_qk_s<8><<<dim3(128, 1, 8), 512, 0, stream>>>(
      x1th, x1tl, wqh, wql, qhg, qlg, 6, 64);

  // channel branch
  cf_dot<<<dim3(16, 8), 256, 0, stream>>>(x1, wc, cfr);
  cf_softmax<<<dim3(8), 1024, 0, stream>>>(cfr, cfs);
  ykern<<<dim3(16, 8), 256, 0, stream>>>(x1, cfs, Tb);
  pool_k<<<dim3(32, 8), 256, 0, stream>>>(Tb, wch, cfr);
  chw_tail<<<dim3(8), 256, 0, stream>>>(cfr, wt1, bt1, lng, lnb, wt2, bt2, cwb);

  // attention
  attn_stats<<<dim3(64, 8), 256, 0, stream>>>(qhg, qlg, khg, klg, mxsb, invb);
  attn_pv<<<dim3(128, 8), 256, 0, stream>>>(qhg, qlg, khg, klg, v16, mxsb, invb, x1, cwb, outp);
}

// Round 9
// 375.451 us; speedup vs baseline: 1.1929x; 1.1131x over previous
//
#include <hip/hip_runtime.h>
#include <stdint.h>

#define LL long long

typedef short short8 __attribute__((ext_vector_type(8)));
typedef float f32x4 __attribute__((ext_vector_type(4)));
typedef unsigned int uint2v __attribute__((ext_vector_type(2)));

__device__ __forceinline__ unsigned short f2bf(float f) {
  unsigned u = __float_as_uint(f);
  unsigned r = (u + 0x7fffu + ((u >> 16) & 1u)) >> 16;
  return (unsigned short)r;
}
__device__ __forceinline__ float bf2f(unsigned short h) {
  return __uint_as_float(((unsigned)h) << 16);
}

#define MFMA16(A, B, C) __builtin_amdgcn_mfma_f32_16x16x32_bf16(A, B, C, 0, 0, 0)

// ======================================================================
// Weight pre-transform: src fp32 [OC][IC][3][3] -> bf16 [9][IC/32][OC][32]
// ======================================================================
__global__ __launch_bounds__(256) void wtrans2(
    const float* __restrict__ src, unsigned short* __restrict__ dh,
    unsigned short* __restrict__ dl, int OC, int IC)
{
  const int i = blockIdx.x * 256 + threadIdx.x;
  if (i >= OC * IC * 9) return;
  const int off = i % 9;
  const int rest = i / 9;
  const int ic = rest % IC;
  const int oc = rest / IC;
  const float v = src[i];
  const unsigned short h = f2bf(v);
  const LL di = (((LL)off * (IC >> 5) + (ic >> 5)) * OC + oc) * 32 + (ic & 31);
  dh[di] = h;
  if (dl) dl[di] = f2bf(v - bf2f(h));
}

// ======================================================================
// transp: src fp32 [B][C][N] -> dh/dl bf16 CHUNKED [B][C/32][N][32]
// ======================================================================
__global__ __launch_bounds__(256) void transp(
    const float* __restrict__ src, unsigned short* __restrict__ dh,
    unsigned short* __restrict__ dl, int C, int N)
{
  __shared__ unsigned short sh[64 * 66];
  __shared__ unsigned short sl[64 * 66];
  const int t = threadIdx.x;
  const int b = blockIdx.z;
  const int n0 = blockIdx.x * 64, c0 = blockIdx.y * 64;
  {
    const int nl = t & 63, cl0 = t >> 6;
#pragma unroll
    for (int i = 0; i < 16; ++i) {
      const int cl = cl0 + 4 * i;
      const float v = src[((LL)b * C + c0 + cl) * N + n0 + nl];
      const unsigned short h = f2bf(v);
      sh[nl * 66 + cl] = h;
      sl[nl * 66 + cl] = f2bf(v - bf2f(h));
    }
  }
  __syncthreads();
  {
    const int cl = t & 63, nr0 = t >> 6;
    const int chunk = (c0 + cl) >> 5;   // c0 is a multiple of 64
    const int cin = cl & 31;
#pragma unroll
    for (int j = 0; j < 16; ++j) {
      const int nr = nr0 + 4 * j;
      const LL di = (((LL)b * (C >> 5) + chunk) * N + n0 + nr) * 32 + cin;
      dh[di] = sh[nr * 66 + cl];
      if (dl) dl[di] = sl[nr * 66 + cl];
    }
  }
}

// ======================================================================
// conv_qk_s<NW>: in-block FULL K-split 3x3 conv, bf16x2, NW waves,
// one 32-ch chunk per wave (C = NW*32). LDS all-wave reduction, then
// bf16 hi/lo split written DIRECTLY. q: NW=8, k: NW=16.
// ======================================================================
template<int NW>
__global__ __launch_bounds__(NW * 64) void conv_qk_s(
    const unsigned short* __restrict__ xh, const unsigned short* __restrict__ xl,
    const unsigned short* __restrict__ wh, const unsigned short* __restrict__ wl,
    unsigned short* __restrict__ dh, unsigned short* __restrict__ dl,
    int logW, int H)
{
  __shared__ float sred[NW][16][64];
  const int t = threadIdx.x, w = t >> 6, lane = t & 63;
  const int lo4 = lane & 15, hi4 = lane >> 4;
  const int b = blockIdx.z;
  const int W = 1 << logW;
  const int N = H * W;
  const int px0 = blockIdx.x * 32;
  const int row = px0 >> logW;       // wave-uniform (32 px within one row)
  const int x0 = px0 & (W - 1);
  const int ch = w;                  // one chunk per wave
  const short8 zero8 = {0, 0, 0, 0, 0, 0, 0, 0};

  f32x4 acc[2][2];
#pragma unroll
  for (int p = 0; p < 2; ++p)
#pragma unroll
    for (int ot = 0; ot < 2; ++ot) acc[p][ot] = (f32x4){0.f, 0.f, 0.f, 0.f};

  const LL xbase = ((LL)(b * NW + ch)) * N * 32 + hi4 * 8;
#pragma unroll
  for (int ky = 0; ky < 3; ++ky) {
    const int gy = row + ky - 1;
    const bool oky = (unsigned)gy < (unsigned)H;
    const int gyc = min(max(gy, 0), H - 1);
#pragma unroll
    for (int kx = 0; kx < 3; ++kx) {
      short8 Bh[2], Bl[2];
#pragma unroll
      for (int p = 0; p < 2; ++p) {
        const int gx = x0 + p * 16 + lo4 + kx - 1;
        const bool ok = oky && ((unsigned)gx < (unsigned)W);
        const int gxc = min(max(gx, 0), W - 1);
        const LL xoff = xbase + (LL)(gyc * W + gxc) * 32;
        const short8 bh = *(const short8*)(xh + xoff);
        const short8 bl = *(const short8*)(xl + xoff);
        Bh[p] = ok ? bh : zero8;
        Bl[p] = ok ? bl : zero8;
      }
      const int off = ky * 3 + kx;
      short8 Ah[2], Al[2];
#pragma unroll
      for (int ot = 0; ot < 2; ++ot) {
        const LL wi = ((LL)(off * NW + ch) * 32 + ot * 16 + lo4) * 32 + hi4 * 8;
        Ah[ot] = *(const short8*)(wh + wi);
        Al[ot] = *(const short8*)(wl + wi);
      }
#pragma unroll
      for (int p = 0; p < 2; ++p)
#pragma unroll
        for (int ot = 0; ot < 2; ++ot) {
          acc[p][ot] = MFMA16(Ah[ot], Bh[p], acc[p][ot]);
          acc[p][ot] = MFMA16(Ah[ot], Bl[p], acc[p][ot]);
          acc[p][ot] = MFMA16(Al[ot], Bh[p], acc[p][ot]);
        }
    }
  }
  // dump all partials to LDS
#pragma unroll
  for (int p = 0; p < 2; ++p)
#pragma unroll
    for (int ot = 0; ot < 2; ++ot)
#pragma unroll
      for (int r = 0; r < 4; ++r)
        sred[w][p * 8 + ot * 4 + r][lane] = acc[p][ot][r];
  __syncthreads();
  // each wave reduces 16/NW slots and writes bf16 hi/lo directly
  constexpr int SPW = 16 / NW;
#pragma unroll
  for (int si = 0; si < SPW; ++si) {
    const int slot = w * SPW + si;
    float v = sred[0][slot][lane];
#pragma unroll
    for (int j = 1; j < NW; ++j) v += sred[j][slot][lane];
    const int p = slot >> 3, ot = (slot >> 2) & 1, r = slot & 3;
    const LL di = ((LL)b * N + px0 + p * 16 + lo4) * 32 + ot * 16 + hi4 * 4 + r;
    const unsigned short h = f2bf(v);
    dh[di] = h;
    dl[di] = f2bf(v - bf2f(h));
  }
}

// ======================================================================
// conv_v_w: row-reuse register-tiled conv. Wave = 4 output rows x 16 px
// x 32 oc, acc[4][2]. A[9][2] staged in regs per ch; 6-row gy sweep
// loads each B fragment ONCE -> 0.5 loads/MFMA.
// ======================================================================
__global__ __launch_bounds__(512) void conv_v_w(
    const unsigned short* __restrict__ xh, const unsigned short* __restrict__ wt,
    unsigned short* __restrict__ out)
{
  __shared__ float sred[4][32][64];
  const int t = threadIdx.x, w = t >> 6, lane = t & 63;
  const int lo4 = lane & 15, hi4 = lane >> 4;
  const int b = blockIdx.z;
  const int h = w & 1, ocg = (w >> 1) & 1, kp = w >> 2;
  const int r0 = blockIdx.x * 4;                      // output rows r0..r0+3
  const int ocb = blockIdx.y * 64 + ocg * 32;         // wave oc base
  const short8 zero8 = {0, 0, 0, 0, 0, 0, 0, 0};

  f32x4 acc[4][2];
#pragma unroll
  for (int rr = 0; rr < 4; ++rr)
#pragma unroll
    for (int ot = 0; ot < 2; ++ot) acc[rr][ot] = (f32x4){0.f, 0.f, 0.f, 0.f};

  for (int ch = kp * 8; ch < kp * 8 + 8; ++ch) {
    short8 A[3][3][2];
#pragma unroll
    for (int ky = 0; ky < 3; ++ky)
#pragma unroll
      for (int kx = 0; kx < 3; ++kx)
#pragma unroll
        for (int ot = 0; ot < 2; ++ot) {
          const int off = ky * 3 + kx;
          A[ky][kx][ot] = *(const short8*)(
              wt + ((LL)(off * 16 + ch) * 256 + ocb + ot * 16 + lo4) * 32 + hi4 * 8);
        }
    const LL xchb = ((LL)(b * 16 + ch)) * 1024 * 32 + hi4 * 8;
#pragma unroll
    for (int g = 0; g < 6; ++g) {
      const int gy = r0 - 1 + g;
      const bool oky = (unsigned)gy < 32u;
      const int gyc = min(max(gy, 0), 31);
      short8 Bg[3];
#pragma unroll
      for (int kx = 0; kx < 3; ++kx) {
        const int gx = h * 16 + lo4 + kx - 1;
        const bool ok = oky && ((unsigned)gx < 32u);
        const int gxc = min(max(gx, 0), 31);
        const short8 bv = *(const short8*)(xh + xchb + (LL)(gyc * 32 + gxc) * 32);
        Bg[kx] = ok ? bv : zero8;
      }
#pragma unroll
      for (int rr = 0; rr < 4; ++rr) {
        if (rr > g || rr + 2 < g) continue;   // compile-time (g, rr unrolled)
        const int ky = g - rr;
#pragma unroll
        for (int kx = 0; kx < 3; ++kx)
#pragma unroll
          for (int ot = 0; ot < 2; ++ot)
            acc[rr][ot] = MFMA16(A[ky][kx][ot], Bg[kx], acc[rr][ot]);
      }
    }
  }
  const int slotbase = h * 2 + ocg;   // 4 (h,ocg) groups
  if (kp == 1) {
#pragma unroll
    for (int rr = 0; rr < 4; ++rr)
#pragma unroll
      for (int ot = 0; ot < 2; ++ot)
#pragma unroll
        for (int r = 0; r < 4; ++r)
          sred[slotbase][rr * 8 + ot * 4 + r][lane] = acc[rr][ot][r];
  }
  __syncthreads();
  if (kp == 0) {
#pragma unroll
    for (int rr = 0; rr < 4; ++rr)
#pragma unroll
      for (int ot = 0; ot < 2; ++ot)
#pragma unroll
        for (int r = 0; r < 4; ++r) {
          const float v = acc[rr][ot][r] + sred[slotbase][rr * 8 + ot * 4 + r][lane];
          const int row = r0 + rr;
          const int oc = ocb + ot * 16 + hi4 * 4 + r;
          out[(((LL)b * 32 + row) * 256 + oc) * 32 + h * 16 + lo4] = f2bf(v);
        }
  }
}

// ======================================================================
// cf[b][n] = sum_c x1[b][c][n] * wc[c]
// ======================================================================
__global__ __launch_bounds__(256) void cf_dot(
    const float* __restrict__ x1, const float* __restrict__ wc, float* __restrict__ cf)
{
  const int b = blockIdx.y;
  const int n = blockIdx.x * 256 + threadIdx.x;
  const float* xp = x1 + (LL)b * 256 * 4096 + n;
  float a = 0.f;
#pragma unroll 4
  for (int c = 0; c < 256; ++c)
    a = fmaf(xp[(LL)c * 4096], wc[c], a);
  cf[b * 4096 + n] = a;
}

// ======================================================================
// softmax over 4096 per batch
// ======================================================================
__global__ __launch_bounds__(1024) void cf_softmax(
    const float* __restrict__ cf, float* __restrict__ cfs)
{
  const int b = blockIdx.x, t = threadIdx.x;
  __shared__ float r1[16];
  __shared__ float r2[16];
  float v[4];
#pragma unroll
  for (int j = 0; j < 4; ++j) v[j] = cf[b * 4096 + t + 1024 * j];
  float mx = fmaxf(fmaxf(v[0], v[1]), fmaxf(v[2], v[3]));
#pragma unroll
  for (int k = 1; k <= 32; k <<= 1) mx = fmaxf(mx, __shfl_xor(mx, k));
  const int wv = t >> 6;
  if ((t & 63) == 0) r1[wv] = mx;
  __syncthreads();
  float m2 = r1[0];
#pragma unroll
  for (int i = 1; i < 16; ++i) m2 = fmaxf(m2, r1[i]);
  float e[4]; float s = 0.f;
#pragma unroll
  for (int j = 0; j < 4; ++j) { e[j] = __expf(v[j] - m2); s += e[j]; }
#pragma unroll
  for (int k = 1; k <= 32; k <<= 1) s += __shfl_xor(s, k);
  if ((t & 63) == 0) r2[wv] = s;
  __syncthreads();
  float s2 = 0.f;
#pragma unroll
  for (int i = 0; i < 16; ++i) s2 += r2[i];
  const float inv = 1.f / s2;
#pragma unroll
  for (int j = 0; j < 4; ++j) cfs[b * 4096 + t + 1024 * j] = e[j] * inv;
}

// ======================================================================
// ykern2: T-partial[b][rowpair][c][9] = sum over 2 rows x 64 cols of
// x1[b][c][y][x] * cfs[b][y+1-dy][x+1-dx].
// 512 thr = 256 c x 2 rows; x-row in regs (full unroll); cfs rows staged
// transposed in LDS -> ONE b128 broadcast read per col (was 9 scalar).
// Atomic-free: h-pair LDS reduction -> partial slab, summed by red_t.
// ======================================================================
__global__ __launch_bounds__(512) void ykern2(
    const float* __restrict__ x1, const float* __restrict__ cfs,
    float* __restrict__ ykp)
{
  __shared__ __align__(16) float cl2[64][4];
  __shared__ float sredY[256][9];
  const int t = threadIdx.x;
  const int c = t & 255, h = t >> 8;
  const int bx = blockIdx.x, b = blockIdx.y;
  const int base = bx * 2;
  if (t < 256) {
    const int r = t >> 6, cc = t & 63;
    const int grow = base - 1 + r;
    cl2[cc][r] = ((unsigned)grow < 64u) ? cfs[b * 4096 + grow * 64 + cc] : 0.f;
  }
  __syncthreads();
  const int row = base + h;
  float xr[66];
  xr[0] = 0.f; xr[65] = 0.f;
  {
    const float4* xp = (const float4*)(x1 + ((LL)(b * 256 + c)) * 4096 + row * 64);
#pragma unroll
    for (int j = 0; j < 16; ++j) {
      const float4 v = xp[j];
      xr[1 + 4 * j] = v.x; xr[2 + 4 * j] = v.y;
      xr[3 + 4 * j] = v.z; xr[4 + 4 * j] = v.w;
    }
  }
  float a[9];
#pragma unroll
  for (int k = 0; k < 9; ++k) a[k] = 0.f;
  const bool h1 = (h == 1);   // wave-uniform
#pragma unroll
  for (int c0 = 0; c0 < 64; ++c0) {
    const float4 f4 = *(const float4*)&cl2[c0][0];
    // F row r-index = h+2-dy
    const float f_dy0 = h1 ? f4.w : f4.z;
    const float f_dy1 = h1 ? f4.z : f4.y;
    const float f_dy2 = h1 ? f4.y : f4.x;
#pragma unroll
    for (int dx = 0; dx < 3; ++dx) {
      const float xv = xr[c0 + dx];   // x[c0-1+dx], +1 pad offset
      a[0 * 3 + dx] = fmaf(xv, f_dy0, a[0 * 3 + dx]);
      a[1 * 3 + dx] = fmaf(xv, f_dy1, a[1 * 3 + dx]);
      a[2 * 3 + dx] = fmaf(xv, f_dy2, a[2 * 3 + dx]);
    }
  }
  if (h1) {
#pragma unroll
    for (int k = 0; k < 9; ++k) sredY[c][k] = a[k];
  }
  __syncthreads();
  if (!h1) {
    float* op = ykp + ((LL)(b * 32 + bx)) * 2304 + c * 9;
#pragma unroll
    for (int k = 0; k < 9; ++k) op[k] = a[k] + sredY[c][k];
  }
}

// ======================================================================
// red_t: T[b][j] = sum over 32 row-pair partials
// ======================================================================
__global__ __launch_bounds__(256) void red_t(
    const float* __restrict__ src, float* __restrict__ dst)
{
  const int b = blockIdx.y;
  const int i = blockIdx.x * 256 + threadIdx.x;   // float4 index < 576
  if (i >= 576) return;
  const f32x4* sp = (const f32x4*)(src + (LL)b * 32 * 2304);
  f32x4 a = sp[i];
  for (int p = 1; p < 32; ++p) a += sp[p * 576 + i];
  ((f32x4*)(dst + (LL)b * 2304))[i] = a;
}

// ======================================================================
// pool_k: pool[b][oc] = wch[oc][:] . T[b][:]  (2304-dot)
// ======================================================================
__global__ __launch_bounds__(256) void pool_k(
    const float* __restrict__ T, const float* __restrict__ wch,
    float* __restrict__ pool)
{
  __shared__ __align__(16) float Tl[2304];
  const int b = blockIdx.y, ocg = blockIdx.x;
  const int t = threadIdx.x, w = t >> 6, lane = t & 63;
  for (int i = t; i < 2304; i += 256) Tl[i] = T[(LL)b * 2304 + i];
  __syncthreads();
  const float4* tp = (const float4*)Tl;
#pragma unroll
  for (int oi = 0; oi < 2; ++oi) {
    const int oc = ocg * 8 + w * 2 + oi;
    const float4* wp = (const float4*)(wch + (LL)oc * 2304);
    float a = 0.f;
#pragma unroll
    for (int j = 0; j < 9; ++j) {
      const int idx = lane + 64 * j;
      float4 w4 = wp[idx], t4 = tp[idx];
      a = fmaf(w4.x, t4.x, a); a = fmaf(w4.y, t4.y, a);
      a = fmaf(w4.z, t4.z, a); a = fmaf(w4.w, t4.w, a);
    }
#pragma unroll
    for (int k = 1; k <= 32; k <<= 1) a += __shfl_xor(a, k);
    if (lane == 0) pool[b * 256 + oc] = a;
  }
}

// ======================================================================
// chw_tail: t1 = wt1.pool + bt1 ; LN(32) ; relu ; cwp1 = 1 + wt2.t + bt2
// ======================================================================
__global__ __launch_bounds__(256) void chw_tail(
    const float* __restrict__ pool_g,
    const float* __restrict__ wt1, const float* __restrict__ bt1,
    const float* __restrict__ lng, const float* __restrict__ lnb,
    const float* __restrict__ wt2, const float* __restrict__ bt2,
    float* __restrict__ cwp1)
{
  const int b = blockIdx.x, t = threadIdx.x;
  __shared__ float pool[256];
  __shared__ float tt[32];
  pool[t] = pool_g[b * 256 + t];
  __syncthreads();
  if (t < 64) {
    float tv = 0.f;
    if (t < 32) {
      const float* wp = wt1 + (LL)t * 256;
      for (int c = 0; c < 256; ++c) tv = fmaf(wp[c], pool[c], tv);
      tv += bt1[t];
    }
    float s = tv;
#pragma unroll
    for (int k = 1; k <= 16; k <<= 1) s += __shfl_xor(s, k);
    float mu = s * (1.f / 32.f);
    float d = tv - mu;
    float vs = d * d;
#pragma unroll
    for (int k = 1; k <= 16; k <<= 1) vs += __shfl_xor(vs, k);
    float var = vs * (1.f / 32.f);
    if (t < 32) {
      float nrm = d / sqrtf(var + 1e-5f);
      float y = nrm * lng[t] + lnb[t];
      tt[t] = fmaxf(y, 0.f);
    }
  }
  __syncthreads();
  {
    float s2 = bt2[t];
    const float* wp = wt2 + (LL)t * 32;
#pragma unroll
    for (int i = 0; i < 32; ++i) s2 = fmaf(wp[i], tt[i], s2);
    cwp1[b * 256 + t] = 1.f + s2;
  }
}

// ======================================================================
// attn_stats: per (b,m) softmax max & inverse-sum over n=1024.
// ======================================================================
__global__ __launch_bounds__(256) void attn_stats(
    const unsigned short* __restrict__ qh_g, const unsigned short* __restrict__ ql_g,
    const unsigned short* __restrict__ kh_g, const unsigned short* __restrict__ kl_g,
    float* __restrict__ mxs, float* __restrict__ invl)
{
  const int t = threadIdx.x, w = t >> 6, lane = t & 63;
  const int lo4 = lane & 15, hi4 = lane >> 4;
  const int b = blockIdx.y, mc = blockIdx.x * 64;
  const float L2E = 1.4426950408889634f;

  short8 qh[4], ql[4];
#pragma unroll
  for (int mt = 0; mt < 4; ++mt) {
    const LL qa = ((LL)(b * 4096 + mc + mt * 16 + lo4)) * 32 + hi4 * 8;
    qh[mt] = *(const short8*)(qh_g + qa);
    ql[mt] = *(const short8*)(ql_g + qa);
  }

  float M[4], L[4];
#pragma unroll
  for (int mt = 0; mt < 4; ++mt) { M[mt] = -1e30f; L[mt] = 0.f; }

  for (int ns = 0; ns < 16; ++ns) {
    const int n = w * 256 + ns * 16 + lo4;
    const LL ka = ((LL)(b * 1024 + n)) * 32 + hi4 * 8;
    const short8 kh = *(const short8*)(kh_g + ka);
    const short8 kl = *(const short8*)(kl_g + ka);
#pragma unroll
    for (int mt = 0; mt < 4; ++mt) {
      f32x4 s = {0.f, 0.f, 0.f, 0.f};
      s = MFMA16(kl, qh[mt], s);
      s = MFMA16(kh, ql[mt], s);
      s = MFMA16(kh, qh[mt], s);
      float lm = fmaxf(fmaxf(s[0], s[1]), fmaxf(s[2], s[3]));
      float nM = fmaxf(M[mt], lm);
      float sc = exp2f((M[mt] - nM) * L2E);
      L[mt] = L[mt] * sc + exp2f((s[0] - nM) * L2E) + exp2f((s[1] - nM) * L2E)
                         + exp2f((s[2] - nM) * L2E) + exp2f((s[3] - nM) * L2E);
      M[mt] = nM;
    }
  }
#pragma unroll
  for (int mask = 16; mask <= 32; mask <<= 1) {
#pragma unroll
    for (int mt = 0; mt < 4; ++mt) {
      float oM = __shfl_xor(M[mt], mask), oL = __shfl_xor(L[mt], mask);
      float nM = fmaxf(M[mt], oM);
      L[mt] = L[mt] * exp2f((M[mt] - nM) * L2E) + oL * exp2f((oM - nM) * L2E);
      M[mt] = nM;
    }
  }
  __shared__ float sM[4][64], sL[4][64];
  if (lane < 16) {
#pragma unroll
    for (int mt = 0; mt < 4; ++mt) {
      sM[w][mt * 16 + lane] = M[mt];
      sL[w][mt * 16 + lane] = L[mt];
    }
  }
  __syncthreads();
  if (t < 64) {
    float Mg = sM[0][t], Lg = sL[0][t];
#pragma unroll
    for (int wv = 1; wv < 4; ++wv) {
      float oM = sM[wv][t], oL = sL[wv][t];
      float nM = fmaxf(Mg, oM);
      Lg = Lg * exp2f((Mg - nM) * L2E) + oL * exp2f((oM - nM) * L2E);
      Mg = nM;
    }
    mxs[b * 4096 + mc + t] = Mg * L2E;
    invl[b * 4096 + mc + t] = 1.f / Lg;
  }
}

// ======================================================================
// attn_pv: fused logits + softmax-apply + PV MFMA + epilogue.
// ======================================================================
__global__ __launch_bounds__(256) void attn_pv(
    const unsigned short* __restrict__ qh_g, const unsigned short* __restrict__ ql_g,
    const unsigned short* __restrict__ kh_g, const unsigned short* __restrict__ kl_g,
    const unsigned short* __restrict__ v16,
    const float* __restrict__ mxs, const float* __restrict__ invl,
    const float* __restrict__ x1, const float* __restrict__ cwp1,
    float* __restrict__ out)
{
  __shared__ __align__(16) unsigned short Pt[2][32][136];
  const int t = threadIdx.x, w = t >> 6, lane = t & 63;
  const int lo4 = lane & 15, hi4 = lane >> 4;
  const int b = blockIdx.y, mb = blockIdx.x * 32;
  const float L2E = 1.4426950408889634f;

  short8 qh[2], ql[2];
  float mxv[2], ilv[2];
#pragma unroll
  for (int mt = 0; mt < 2; ++mt) {
    const int m = mb + mt * 16 + lo4;
    const LL qa = ((LL)(b * 4096 + m)) * 32 + hi4 * 8;
    qh[mt] = *(const short8*)(qh_g + qa);
    ql[mt] = *(const short8*)(ql_g + qa);
    mxv[mt] = mxs[b * 4096 + m];
    ilv[mt] = invl[b * 4096 + m];
  }

  f32x4 acc[4][2];
#pragma unroll
  for (int ct = 0; ct < 4; ++ct)
#pragma unroll
    for (int mt = 0; mt < 2; ++mt) acc[ct][mt] = (f32x4){0.f, 0.f, 0.f, 0.f};

  short8 kh[2], kl[2];
#pragma unroll
  for (int ns = 0; ns < 2; ++ns) {
    const LL ka = ((LL)(b * 1024 + w * 32 + ns * 16 + lo4)) * 32 + hi4 * 8;
    kh[ns] = *(const short8*)(kh_g + ka);
    kl[ns] = *(const short8*)(kl_g + ka);
  }

  int buf = 0;
  for (int nt = 0; nt < 8; ++nt) {
    short8 knh[2], knl[2];
    {
      const int ntn = (nt + 1) & 7;
#pragma unroll
      for (int ns = 0; ns < 2; ++ns) {
        const LL ka = ((LL)(b * 1024 + ntn * 128 + w * 32 + ns * 16 + lo4)) * 32 + hi4 * 8;
        knh[ns] = *(const short8*)(kh_g + ka);
        knl[ns] = *(const short8*)(kl_g + ka);
      }
    }
    f32x4 s[2][2];
#pragma unroll
    for (int ns = 0; ns < 2; ++ns)
#pragma unroll
      for (int mt = 0; mt < 2; ++mt) {
        f32x4 z = {0.f, 0.f, 0.f, 0.f};
        z = MFMA16(kl[ns], qh[mt], z);
        z = MFMA16(kh[ns], ql[mt], z);
        z = MFMA16(kh[ns], qh[mt], z);
        s[ns][mt] = z;
      }
    short8 vpre[2][4];
#pragma unroll
    for (int ks = 0; ks < 2; ++ks)
#pragma unroll
      for (int ct = 0; ct < 4; ++ct)
        vpre[ks][ct] = *(const short8*)(
            v16 + (((LL)b * 32 + nt * 4 + ks) * 256 + w * 64 + ct * 16 + lo4) * 32 + hi4 * 8);
#pragma unroll
    for (int ns = 0; ns < 2; ++ns)
#pragma unroll
      for (int mt = 0; mt < 2; ++mt) {
        const int m_loc = mt * 16 + lo4;
        const int nl = w * 32 + ns * 16 + hi4 * 4;
        float p0 = exp2f(fmaf(s[ns][mt][0], L2E, -mxv[mt])) * ilv[mt];
        float p1 = exp2f(fmaf(s[ns][mt][1], L2E, -mxv[mt])) * ilv[mt];
        float p2 = exp2f(fmaf(s[ns][mt][2], L2E, -mxv[mt])) * ilv[mt];
        float p3 = exp2f(fmaf(s[ns][mt][3], L2E, -mxv[mt])) * ilv[mt];
        uint2v u;
        u[0] = (unsigned)f2bf(p0) | ((unsigned)f2bf(p1) << 16);
        u[1] = (unsigned)f2bf(p2) | ((unsigned)f2bf(p3) << 16);
        *(uint2v*)&Pt[buf][m_loc][nl] = u;
      }
    __syncthreads();
#pragma unroll
    for (int ks = 0; ks < 4; ++ks) {
      short8 pb[2];
#pragma unroll
      for (int mt = 0; mt < 2; ++mt)
        pb[mt] = *(const short8*)&Pt[buf][mt * 16 + lo4][ks * 32 + hi4 * 8];
#pragma unroll
      for (int ct = 0; ct < 4; ++ct) {
        const short8 va = (ks < 2)
            ? vpre[ks][ct]
            : *(const short8*)(
                  v16 + (((LL)b * 32 + nt * 4 + ks) * 256 + w * 64 + ct * 16 + lo4) * 32 + hi4 * 8);
#pragma unroll
        for (int mt = 0; mt < 2; ++mt)
          acc[ct][mt] = MFMA16(va, pb[mt], acc[ct][mt]);
      }
    }
    buf ^= 1;
#pragma unroll
    for (int ns = 0; ns < 2; ++ns) { kh[ns] = knh[ns]; kl[ns] = knl[ns]; }
  }

#pragma unroll
  for (int ct = 0; ct < 4; ++ct)
#pragma unroll
    for (int mt = 0; mt < 2; ++mt) {
      const int m = mb + mt * 16 + lo4;
#pragma unroll
      for (int r = 0; r < 4; ++r) {
        const int c = w * 64 + ct * 16 + hi4 * 4 + r;
        const float cw = cwp1[b * 256 + c];
        const LL off = ((LL)(b * 256 + c)) * 4096 + m;
        out[off] = acc[ct][mt][r] + x1[off] * cw;
      }
    }
}

// ======================================================================
// launch
// ======================================================================
extern "C" void kernel_launch(void* const* d_in, const int* in_sizes, int n_in,
                              void* d_out, int out_size, void* d_ws, size_t ws_size,
                              hipStream_t stream) {
  const float* x1  = (const float*)d_in[0];
  const float* x2  = (const float*)d_in[1];
  const float* wq  = (const float*)d_in[2];
  const float* wk  = (const float*)d_in[3];
  const float* wv  = (const float*)d_in[4];
  const float* wc  = (const float*)d_in[5];
  const float* wch = (const float*)d_in[6];
  const float* wt1 = (const float*)d_in[7];
  const float* bt1 = (const float*)d_in[8];
  const float* lng = (const float*)d_in[9];
  const float* lnb = (const float*)d_in[10];
  const float* wt2 = (const float*)d_in[11];
  const float* bt2 = (const float*)d_in[12];
  float* outp = (float*)d_out;

  // ---- workspace (carve floats first, then shorts) ----
  float* ws   = (float*)d_ws;
  float* qtf  = ws;                      // q bf16 hi/lo region: 1,048,576 f
  float* ktf  = qtf + 1048576;           // k bf16 hi/lo region:   262,144 f
  float* mxsb = ktf + 262144;            //    32,768 f
  float* invb = mxsb + 32768;            //    32,768 f
  float* cfr  = invb + 32768;            //    32,768 f
  float* cfs  = cfr + 32768;             //    32,768 f
  float* Tb   = cfs + 32768;             //    18,432 f
  float* cwb  = Tb + 18432;              //     2,048 f
  unsigned short* sbase = (unsigned short*)(cwb + 2048);
  unsigned short* v16  = sbase;          // CHUNKED [8][32][256][32]  2,097,152 sh
  unsigned short* x1th = v16  + 2097152; // [8][8][4096][32]     8,388,608 sh
  unsigned short* x1tl = x1th + 8388608;
  unsigned short* x2th = x1tl + 8388608; // [8][16][1024][32]    4,194,304 sh
  unsigned short* x2tl = x2th + 4194304;
  unsigned short* wvt  = x2tl + 4194304; // [9][16][256][32]     1,179,648 sh
  unsigned short* wqh  = wvt  + 1179648; // [9][8][32][32]          73,728 sh
  unsigned short* wql  = wqh  + 73728;
  unsigned short* wkh  = wql  + 73728;   // [9][16][32][32]        147,456 sh
  unsigned short* wkl  = wkh  + 147456;

  // bf16 hi/lo attn operands (alias the fp32 regions exactly):
  unsigned short* qhg = (unsigned short*)qtf;   // [8][4096][32] sh
  unsigned short* qlg = qhg + 1048576;
  unsigned short* khg = (unsigned short*)ktf;   // [8][1024][32] sh
  unsigned short* klg = khg + 262144;

  // ykern partial slab: [8][32][2304] f = 2.36 MB, aliases dead x2 region
  float* ykp = (float*)x2th;

  // weight pre-transforms ([9][IC/32][OC][32])
  wtrans2<<<dim3(4608), 256, 0, stream>>>(wv, wvt, nullptr, 256, 512);
  wtrans2<<<dim3(288),  256, 0, stream>>>(wq, wqh, wql, 32, 256);
  wtrans2<<<dim3(576),  256, 0, stream>>>(wk, wkh, wkl, 32, 512);

  // input transposes: [b][c][n] fp32 -> chunked [b][c/32][n][32] bf16 hi/lo
  transp<<<dim3(64, 4, 8), 256, 0, stream>>>(x1, x1th, x1tl, 256, 4096);
  transp<<<dim3(16, 8, 8), 256, 0, stream>>>(x2, x2th, x2tl, 512, 1024);

  // k conv (x2, C=512): 16 waves, full in-block K-split, direct bf16 out
  conv_qk_s<16><<<dim3(32, 1, 8), 1024, 0, stream>>>(
      x2th, x2tl, wkh, wkl, khg, klg, 5, 32);

  // v conv (x2): row-reuse register-tiled, 0.5 loads/MFMA
  conv_v_w<<<dim3(8, 4, 8), 512, 0, stream>>>(x2th, wvt, v16);

  // q conv (x1, C=256): 8 waves, full in-block K-split, direct bf16 out
  conv_qk_s<8><<<dim3(128, 1, 8), 512, 0, stream>>>(
      x1th, x1tl, wqh, wql, qhg, qlg, 6, 64);

  // channel branch (x2 region now dead -> ykp aliases it)
  cf_dot<<<dim3(16, 8), 256, 0, stream>>>(x1, wc, cfr);
  cf_softmax<<<dim3(8), 1024, 0, stream>>>(cfr, cfs);
  ykern2<<<dim3(32, 8), 512, 0, stream>>>(x1, cfs, ykp);
  red_t<<<dim3(3, 8), 256, 0, stream>>>(ykp, Tb);
  pool_k<<<dim3(32, 8), 256, 0, stream>>>(Tb, wch, cfr);
  chw_tail<<<dim3(8), 256, 0, stream>>>(cfr, wt1, bt1, lng, lnb, wt2, bt2, cwb);

  // attention
  attn_stats<<<dim3(64, 8), 256, 0, stream>>>(qhg, qlg, khg, klg, mxsb, invb);
  attn_pv<<<dim3(128, 8), 256, 0, stream>>>(qhg, qlg, khg, klg, v16, mxsb, invb, x1, cwb, outp);
}

// Round 10
// 361.499 us; speedup vs baseline: 1.2389x; 1.0386x over previous
//
#include <hip/hip_runtime.h>
#include <stdint.h>

#define LL long long

typedef short short8 __attribute__((ext_vector_type(8)));
typedef float f32x4 __attribute__((ext_vector_type(4)));
typedef unsigned int uint2v __attribute__((ext_vector_type(2)));

__device__ __forceinline__ unsigned short f2bf(float f) {
  unsigned u = __float_as_uint(f);
  unsigned r = (u + 0x7fffu + ((u >> 16) & 1u)) >> 16;
  return (unsigned short)r;
}
__device__ __forceinline__ float bf2f(unsigned short h) {
  return __uint_as_float(((unsigned)h) << 16);
}

#define MFMA16(A, B, C) __builtin_amdgcn_mfma_f32_16x16x32_bf16(A, B, C, 0, 0, 0)

// ======================================================================
// Weight pre-transform: src fp32 [OC][IC][3][3] -> bf16 [9][IC/32][OC][32]
// ======================================================================
__global__ __launch_bounds__(256) void wtrans2(
    const float* __restrict__ src, unsigned short* __restrict__ dh,
    unsigned short* __restrict__ dl, int OC, int IC)
{
  const int i = blockIdx.x * 256 + threadIdx.x;
  if (i >= OC * IC * 9) return;
  const int off = i % 9;
  const int rest = i / 9;
  const int ic = rest % IC;
  const int oc = rest / IC;
  const float v = src[i];
  const unsigned short h = f2bf(v);
  const LL di = (((LL)off * (IC >> 5) + (ic >> 5)) * OC + oc) * 32 + (ic & 31);
  dh[di] = h;
  if (dl) dl[di] = f2bf(v - bf2f(h));
}

// ======================================================================
// transp: src fp32 [B][C][N] -> dh/dl bf16 CHUNKED [B][C/32][N][32]
// ======================================================================
__global__ __launch_bounds__(256) void transp(
    const float* __restrict__ src, unsigned short* __restrict__ dh,
    unsigned short* __restrict__ dl, int C, int N)
{
  __shared__ unsigned short sh[64 * 66];
  __shared__ unsigned short sl[64 * 66];
  const int t = threadIdx.x;
  const int b = blockIdx.z;
  const int n0 = blockIdx.x * 64, c0 = blockIdx.y * 64;
  {
    const int nl = t & 63, cl0 = t >> 6;
#pragma unroll
    for (int i = 0; i < 16; ++i) {
      const int cl = cl0 + 4 * i;
      const float v = src[((LL)b * C + c0 + cl) * N + n0 + nl];
      const unsigned short h = f2bf(v);
      sh[nl * 66 + cl] = h;
      sl[nl * 66 + cl] = f2bf(v - bf2f(h));
    }
  }
  __syncthreads();
  {
    const int cl = t & 63, nr0 = t >> 6;
    const int chunk = (c0 + cl) >> 5;   // c0 is a multiple of 64
    const int cin = cl & 31;
#pragma unroll
    for (int j = 0; j < 16; ++j) {
      const int nr = nr0 + 4 * j;
      const LL di = (((LL)b * (C >> 5) + chunk) * N + n0 + nr) * 32 + cin;
      dh[di] = sh[nr * 66 + cl];
      if (dl) dl[di] = sl[nr * 66 + cl];
    }
  }
}

// ======================================================================
// conv_qk_s<NW>: in-block FULL K-split 3x3 conv, bf16x2, NW waves,
// one 32-ch chunk per wave (C = NW*32). LDS all-wave reduction, then
// bf16 hi/lo split written DIRECTLY. q: NW=8, k: NW=16.
// ======================================================================
template<int NW>
__global__ __launch_bounds__(NW * 64) void conv_qk_s(
    const unsigned short* __restrict__ xh, const unsigned short* __restrict__ xl,
    const unsigned short* __restrict__ wh, const unsigned short* __restrict__ wl,
    unsigned short* __restrict__ dh, unsigned short* __restrict__ dl,
    int logW, int H)
{
  __shared__ float sred[NW][16][64];
  const int t = threadIdx.x, w = t >> 6, lane = t & 63;
  const int lo4 = lane & 15, hi4 = lane >> 4;
  const int b = blockIdx.z;
  const int W = 1 << logW;
  const int N = H * W;
  const int px0 = blockIdx.x * 32;
  const int row = px0 >> logW;       // wave-uniform (32 px within one row)
  const int x0 = px0 & (W - 1);
  const int ch = w;                  // one chunk per wave
  const short8 zero8 = {0, 0, 0, 0, 0, 0, 0, 0};

  f32x4 acc[2][2];
#pragma unroll
  for (int p = 0; p < 2; ++p)
#pragma unroll
    for (int ot = 0; ot < 2; ++ot) acc[p][ot] = (f32x4){0.f, 0.f, 0.f, 0.f};

  const LL xbase = ((LL)(b * NW + ch)) * N * 32 + hi4 * 8;
#pragma unroll
  for (int ky = 0; ky < 3; ++ky) {
    const int gy = row + ky - 1;
    const bool oky = (unsigned)gy < (unsigned)H;
    const int gyc = min(max(gy, 0), H - 1);
#pragma unroll
    for (int kx = 0; kx < 3; ++kx) {
      short8 Bh[2], Bl[2];
#pragma unroll
      for (int p = 0; p < 2; ++p) {
        const int gx = x0 + p * 16 + lo4 + kx - 1;
        const bool ok = oky && ((unsigned)gx < (unsigned)W);
        const int gxc = min(max(gx, 0), W - 1);
        const LL xoff = xbase + (LL)(gyc * W + gxc) * 32;
        const short8 bh = *(const short8*)(xh + xoff);
        const short8 bl = *(const short8*)(xl + xoff);
        Bh[p] = ok ? bh : zero8;
        Bl[p] = ok ? bl : zero8;
      }
      const int off = ky * 3 + kx;
      short8 Ah[2], Al[2];
#pragma unroll
      for (int ot = 0; ot < 2; ++ot) {
        const LL wi = ((LL)(off * NW + ch) * 32 + ot * 16 + lo4) * 32 + hi4 * 8;
        Ah[ot] = *(const short8*)(wh + wi);
        Al[ot] = *(const short8*)(wl + wi);
      }
#pragma unroll
      for (int p = 0; p < 2; ++p)
#pragma unroll
        for (int ot = 0; ot < 2; ++ot) {
          acc[p][ot] = MFMA16(Ah[ot], Bh[p], acc[p][ot]);
          acc[p][ot] = MFMA16(Ah[ot], Bl[p], acc[p][ot]);
          acc[p][ot] = MFMA16(Al[ot], Bh[p], acc[p][ot]);
        }
    }
  }
  // dump all partials to LDS
#pragma unroll
  for (int p = 0; p < 2; ++p)
#pragma unroll
    for (int ot = 0; ot < 2; ++ot)
#pragma unroll
      for (int r = 0; r < 4; ++r)
        sred[w][p * 8 + ot * 4 + r][lane] = acc[p][ot][r];
  __syncthreads();
  // each wave reduces 16/NW slots and writes bf16 hi/lo directly
  constexpr int SPW = 16 / NW;
#pragma unroll
  for (int si = 0; si < SPW; ++si) {
    const int slot = w * SPW + si;
    float v = sred[0][slot][lane];
#pragma unroll
    for (int j = 1; j < NW; ++j) v += sred[j][slot][lane];
    const int p = slot >> 3, ot = (slot >> 2) & 1, r = slot & 3;
    const LL di = ((LL)b * N + px0 + p * 16 + lo4) * 32 + ot * 16 + hi4 * 4 + r;
    const unsigned short h = f2bf(v);
    dh[di] = h;
    dl[di] = f2bf(v - bf2f(h));
  }
}

// ======================================================================
// conv_v_w: row-reuse register-tiled conv. Wave = 4 output rows x 16 px
// x 32 oc, acc[4][2]. A[9][2] staged in regs per ch; 6-row gy sweep
// loads each B fragment ONCE -> 0.5 loads/MFMA.
// ======================================================================
__global__ __launch_bounds__(512) void conv_v_w(
    const unsigned short* __restrict__ xh, const unsigned short* __restrict__ wt,
    unsigned short* __restrict__ out)
{
  __shared__ float sred[4][32][64];
  const int t = threadIdx.x, w = t >> 6, lane = t & 63;
  const int lo4 = lane & 15, hi4 = lane >> 4;
  const int b = blockIdx.z;
  const int h = w & 1, ocg = (w >> 1) & 1, kp = w >> 2;
  const int r0 = blockIdx.x * 4;                      // output rows r0..r0+3
  const int ocb = blockIdx.y * 64 + ocg * 32;         // wave oc base
  const short8 zero8 = {0, 0, 0, 0, 0, 0, 0, 0};

  f32x4 acc[4][2];
#pragma unroll
  for (int rr = 0; rr < 4; ++rr)
#pragma unroll
    for (int ot = 0; ot < 2; ++ot) acc[rr][ot] = (f32x4){0.f, 0.f, 0.f, 0.f};

  for (int ch = kp * 8; ch < kp * 8 + 8; ++ch) {
    short8 A[3][3][2];
#pragma unroll
    for (int ky = 0; ky < 3; ++ky)
#pragma unroll
      for (int kx = 0; kx < 3; ++kx)
#pragma unroll
        for (int ot = 0; ot < 2; ++ot) {
          const int off = ky * 3 + kx;
          A[ky][kx][ot] = *(const short8*)(
              wt + ((LL)(off * 16 + ch) * 256 + ocb + ot * 16 + lo4) * 32 + hi4 * 8);
        }
    const LL xchb = ((LL)(b * 16 + ch)) * 1024 * 32 + hi4 * 8;
#pragma unroll
    for (int g = 0; g < 6; ++g) {
      const int gy = r0 - 1 + g;
      const bool oky = (unsigned)gy < 32u;
      const int gyc = min(max(gy, 0), 31);
      short8 Bg[3];
#pragma unroll
      for (int kx = 0; kx < 3; ++kx) {
        const int gx = h * 16 + lo4 + kx - 1;
        const bool ok = oky && ((unsigned)gx < 32u);
        const int gxc = min(max(gx, 0), 31);
        const short8 bv = *(const short8*)(xh + xchb + (LL)(gyc * 32 + gxc) * 32);
        Bg[kx] = ok ? bv : zero8;
      }
#pragma unroll
      for (int rr = 0; rr < 4; ++rr) {
        if (rr > g || rr + 2 < g) continue;   // compile-time (g, rr unrolled)
        const int ky = g - rr;
#pragma unroll
        for (int kx = 0; kx < 3; ++kx)
#pragma unroll
          for (int ot = 0; ot < 2; ++ot)
            acc[rr][ot] = MFMA16(A[ky][kx][ot], Bg[kx], acc[rr][ot]);
      }
    }
  }
  const int slotbase = h * 2 + ocg;   // 4 (h,ocg) groups
  if (kp == 1) {
#pragma unroll
    for (int rr = 0; rr < 4; ++rr)
#pragma unroll
      for (int ot = 0; ot < 2; ++ot)
#pragma unroll
        for (int r = 0; r < 4; ++r)
          sred[slotbase][rr * 8 + ot * 4 + r][lane] = acc[rr][ot][r];
  }
  __syncthreads();
  if (kp == 0) {
#pragma unroll
    for (int rr = 0; rr < 4; ++rr)
#pragma unroll
      for (int ot = 0; ot < 2; ++ot)
#pragma unroll
        for (int r = 0; r < 4; ++r) {
          const float v = acc[rr][ot][r] + sred[slotbase][rr * 8 + ot * 4 + r][lane];
          const int row = r0 + rr;
          const int oc = ocb + ot * 16 + hi4 * 4 + r;
          out[(((LL)b * 32 + row) * 256 + oc) * 32 + h * 16 + lo4] = f2bf(v);
        }
  }
}

// ======================================================================
// cf[b][n] = sum_c x1[b][c][n] * wc[c]
// ======================================================================
__global__ __launch_bounds__(256) void cf_dot(
    const float* __restrict__ x1, const float* __restrict__ wc, float* __restrict__ cf)
{
  const int b = blockIdx.y;
  const int n = blockIdx.x * 256 + threadIdx.x;
  const float* xp = x1 + (LL)b * 256 * 4096 + n;
  float a = 0.f;
#pragma unroll 4
  for (int c = 0; c < 256; ++c)
    a = fmaf(xp[(LL)c * 4096], wc[c], a);
  cf[b * 4096 + n] = a;
}

// ======================================================================
// softmax over 4096 per batch
// ======================================================================
__global__ __launch_bounds__(1024) void cf_softmax(
    const float* __restrict__ cf, float* __restrict__ cfs)
{
  const int b = blockIdx.x, t = threadIdx.x;
  __shared__ float r1[16];
  __shared__ float r2[16];
  float v[4];
#pragma unroll
  for (int j = 0; j < 4; ++j) v[j] = cf[b * 4096 + t + 1024 * j];
  float mx = fmaxf(fmaxf(v[0], v[1]), fmaxf(v[2], v[3]));
#pragma unroll
  for (int k = 1; k <= 32; k <<= 1) mx = fmaxf(mx, __shfl_xor(mx, k));
  const int wv = t >> 6;
  if ((t & 63) == 0) r1[wv] = mx;
  __syncthreads();
  float m2 = r1[0];
#pragma unroll
  for (int i = 1; i < 16; ++i) m2 = fmaxf(m2, r1[i]);
  float e[4]; float s = 0.f;
#pragma unroll
  for (int j = 0; j < 4; ++j) { e[j] = __expf(v[j] - m2); s += e[j]; }
#pragma unroll
  for (int k = 1; k <= 32; k <<= 1) s += __shfl_xor(s, k);
  if ((t & 63) == 0) r2[wv] = s;
  __syncthreads();
  float s2 = 0.f;
#pragma unroll
  for (int i = 0; i < 16; ++i) s2 += r2[i];
  const float inv = 1.f / s2;
#pragma unroll
  for (int j = 0; j < 4; ++j) cfs[b * 4096 + t + 1024 * j] = e[j] * inv;
}

// ======================================================================
// ykern2: T-partial[b][rowpair][c][9]; 512 thr = 256 c x 2 rows.
// ======================================================================
__global__ __launch_bounds__(512) void ykern2(
    const float* __restrict__ x1, const float* __restrict__ cfs,
    float* __restrict__ ykp)
{
  __shared__ __align__(16) float cl2[64][4];
  __shared__ float sredY[256][9];
  const int t = threadIdx.x;
  const int c = t & 255, h = t >> 8;
  const int bx = blockIdx.x, b = blockIdx.y;
  const int base = bx * 2;
  if (t < 256) {
    const int r = t >> 6, cc = t & 63;
    const int grow = base - 1 + r;
    cl2[cc][r] = ((unsigned)grow < 64u) ? cfs[b * 4096 + grow * 64 + cc] : 0.f;
  }
  __syncthreads();
  const int row = base + h;
  float xr[66];
  xr[0] = 0.f; xr[65] = 0.f;
  {
    const float4* xp = (const float4*)(x1 + ((LL)(b * 256 + c)) * 4096 + row * 64);
#pragma unroll
    for (int j = 0; j < 16; ++j) {
      const float4 v = xp[j];
      xr[1 + 4 * j] = v.x; xr[2 + 4 * j] = v.y;
      xr[3 + 4 * j] = v.z; xr[4 + 4 * j] = v.w;
    }
  }
  float a[9];
#pragma unroll
  for (int k = 0; k < 9; ++k) a[k] = 0.f;
  const bool h1 = (h == 1);   // wave-uniform
#pragma unroll
  for (int c0 = 0; c0 < 64; ++c0) {
    const float4 f4 = *(const float4*)&cl2[c0][0];
    const float f_dy0 = h1 ? f4.w : f4.z;
    const float f_dy1 = h1 ? f4.z : f4.y;
    const float f_dy2 = h1 ? f4.y : f4.x;
#pragma unroll
    for (int dx = 0; dx < 3; ++dx) {
      const float xv = xr[c0 + dx];   // x[c0-1+dx], +1 pad offset
      a[0 * 3 + dx] = fmaf(xv, f_dy0, a[0 * 3 + dx]);
      a[1 * 3 + dx] = fmaf(xv, f_dy1, a[1 * 3 + dx]);
      a[2 * 3 + dx] = fmaf(xv, f_dy2, a[2 * 3 + dx]);
    }
  }
  if (h1) {
#pragma unroll
    for (int k = 0; k < 9; ++k) sredY[c][k] = a[k];
  }
  __syncthreads();
  if (!h1) {
    float* op = ykp + ((LL)(b * 32 + bx)) * 2304 + c * 9;
#pragma unroll
    for (int k = 0; k < 9; ++k) op[k] = a[k] + sredY[c][k];
  }
}

// ======================================================================
// red_t: T[b][j] = sum over 32 row-pair partials
// ======================================================================
__global__ __launch_bounds__(256) void red_t(
    const float* __restrict__ src, float* __restrict__ dst)
{
  const int b = blockIdx.y;
  const int i = blockIdx.x * 256 + threadIdx.x;   // float4 index < 576
  if (i >= 576) return;
  const f32x4* sp = (const f32x4*)(src + (LL)b * 32 * 2304);
  f32x4 a = sp[i];
  for (int p = 1; p < 32; ++p) a += sp[p * 576 + i];
  ((f32x4*)(dst + (LL)b * 2304))[i] = a;
}

// ======================================================================
// pool_k: pool[b][oc] = wch[oc][:] . T[b][:]  (2304-dot)
// ======================================================================
__global__ __launch_bounds__(256) void pool_k(
    const float* __restrict__ T, const float* __restrict__ wch,
    float* __restrict__ pool)
{
  __shared__ __align__(16) float Tl[2304];
  const int b = blockIdx.y, ocg = blockIdx.x;
  const int t = threadIdx.x, w = t >> 6, lane = t & 63;
  for (int i = t; i < 2304; i += 256) Tl[i] = T[(LL)b * 2304 + i];
  __syncthreads();
  const float4* tp = (const float4*)Tl;
#pragma unroll
  for (int oi = 0; oi < 2; ++oi) {
    const int oc = ocg * 8 + w * 2 + oi;
    const float4* wp = (const float4*)(wch + (LL)oc * 2304);
    float a = 0.f;
#pragma unroll
    for (int j = 0; j < 9; ++j) {
      const int idx = lane + 64 * j;
      float4 w4 = wp[idx], t4 = tp[idx];
      a = fmaf(w4.x, t4.x, a); a = fmaf(w4.y, t4.y, a);
      a = fmaf(w4.z, t4.z, a); a = fmaf(w4.w, t4.w, a);
    }
#pragma unroll
    for (int k = 1; k <= 32; k <<= 1) a += __shfl_xor(a, k);
    if (lane == 0) pool[b * 256 + oc] = a;
  }
}

// ======================================================================
// chw_tail: t1 = wt1.pool + bt1 ; LN(32) ; relu ; cwp1 = 1 + wt2.t + bt2
// ======================================================================
__global__ __launch_bounds__(256) void chw_tail(
    const float* __restrict__ pool_g,
    const float* __restrict__ wt1, const float* __restrict__ bt1,
    const float* __restrict__ lng, const float* __restrict__ lnb,
    const float* __restrict__ wt2, const float* __restrict__ bt2,
    float* __restrict__ cwp1)
{
  const int b = blockIdx.x, t = threadIdx.x;
  __shared__ float pool[256];
  __shared__ float tt[32];
  pool[t] = pool_g[b * 256 + t];
  __syncthreads();
  if (t < 64) {
    float tv = 0.f;
    if (t < 32) {
      const float* wp = wt1 + (LL)t * 256;
      for (int c = 0; c < 256; ++c) tv = fmaf(wp[c], pool[c], tv);
      tv += bt1[t];
    }
    float s = tv;
#pragma unroll
    for (int k = 1; k <= 16; k <<= 1) s += __shfl_xor(s, k);
    float mu = s * (1.f / 32.f);
    float d = tv - mu;
    float vs = d * d;
#pragma unroll
    for (int k = 1; k <= 16; k <<= 1) vs += __shfl_xor(vs, k);
    float var = vs * (1.f / 32.f);
    if (t < 32) {
      float nrm = d / sqrtf(var + 1e-5f);
      float y = nrm * lng[t] + lnb[t];
      tt[t] = fmaxf(y, 0.f);
    }
  }
  __syncthreads();
  {
    float s2 = bt2[t];
    const float* wp = wt2 + (LL)t * 32;
#pragma unroll
    for (int i = 0; i < 32; ++i) s2 = fmaf(wp[i], tt[i], s2);
    cwp1[b * 256 + t] = 1.f + s2;
  }
}

// ======================================================================
// attn_stats: per (b,m) fused softmax constant sub = -(M*log2e + log2(L))
// so pv computes p = exp2(fma(s, L2E, sub)) = exp(s-M)/L.
// ======================================================================
__global__ __launch_bounds__(256) void attn_stats(
    const unsigned short* __restrict__ qh_g, const unsigned short* __restrict__ ql_g,
    const unsigned short* __restrict__ kh_g, const unsigned short* __restrict__ kl_g,
    float* __restrict__ subb)
{
  const int t = threadIdx.x, w = t >> 6, lane = t & 63;
  const int lo4 = lane & 15, hi4 = lane >> 4;
  const int b = blockIdx.y, mc = blockIdx.x * 64;
  const float L2E = 1.4426950408889634f;

  short8 qh[4], ql[4];
#pragma unroll
  for (int mt = 0; mt < 4; ++mt) {
    const LL qa = ((LL)(b * 4096 + mc + mt * 16 + lo4)) * 32 + hi4 * 8;
    qh[mt] = *(const short8*)(qh_g + qa);
    ql[mt] = *(const short8*)(ql_g + qa);
  }

  float M[4], L[4];
#pragma unroll
  for (int mt = 0; mt < 4; ++mt) { M[mt] = -1e30f; L[mt] = 0.f; }

  for (int ns = 0; ns < 16; ++ns) {
    const int n = w * 256 + ns * 16 + lo4;
    const LL ka = ((LL)(b * 1024 + n)) * 32 + hi4 * 8;
    const short8 kh = *(const short8*)(kh_g + ka);
    const short8 kl = *(const short8*)(kl_g + ka);
#pragma unroll
    for (int mt = 0; mt < 4; ++mt) {
      f32x4 s = {0.f, 0.f, 0.f, 0.f};
      s = MFMA16(kl, qh[mt], s);
      s = MFMA16(kh, ql[mt], s);
      s = MFMA16(kh, qh[mt], s);
      float lm = fmaxf(fmaxf(s[0], s[1]), fmaxf(s[2], s[3]));
      float nM = fmaxf(M[mt], lm);
      float sc = exp2f((M[mt] - nM) * L2E);
      L[mt] = L[mt] * sc + exp2f((s[0] - nM) * L2E) + exp2f((s[1] - nM) * L2E)
                         + exp2f((s[2] - nM) * L2E) + exp2f((s[3] - nM) * L2E);
      M[mt] = nM;
    }
  }
#pragma unroll
  for (int mask = 16; mask <= 32; mask <<= 1) {
#pragma unroll
    for (int mt = 0; mt < 4; ++mt) {
      float oM = __shfl_xor(M[mt], mask), oL = __shfl_xor(L[mt], mask);
      float nM = fmaxf(M[mt], oM);
      L[mt] = L[mt] * exp2f((M[mt] - nM) * L2E) + oL * exp2f((oM - nM) * L2E);
      M[mt] = nM;
    }
  }
  __shared__ float sM[4][64], sL[4][64];
  if (lane < 16) {
#pragma unroll
    for (int mt = 0; mt < 4; ++mt) {
      sM[w][mt * 16 + lane] = M[mt];
      sL[w][mt * 16 + lane] = L[mt];
    }
  }
  __syncthreads();
  if (t < 64) {
    float Mg = sM[0][t], Lg = sL[0][t];
#pragma unroll
    for (int wv = 1; wv < 4; ++wv) {
      float oM = sM[wv][t], oL = sL[wv][t];
      float nM = fmaxf(Mg, oM);
      Lg = Lg * exp2f((Mg - nM) * L2E) + oL * exp2f((oM - nM) * L2E);
      Mg = nM;
    }
    subb[b * 4096 + mc + t] = -(Mg * L2E + log2f(Lg));
  }
}

// ======================================================================
// attn_pv: fused logits + softmax-apply + PV MFMA + epilogue.
// mt=4 (64 Q-rows/block): V-loads feed 4 MFMAs, K-loads 6 -> loads/MFMA
// halved vs mt=2. Pt padded to 140 shorts (70-dword stride, bank-spread).
// Per-ns logits->softmax shrinks register live ranges; V prefetch first.
// ======================================================================
__global__ __launch_bounds__(256, 2) void attn_pv(
    const unsigned short* __restrict__ qh_g, const unsigned short* __restrict__ ql_g,
    const unsigned short* __restrict__ kh_g, const unsigned short* __restrict__ kl_g,
    const unsigned short* __restrict__ v16,
    const float* __restrict__ subb,
    const float* __restrict__ x1, const float* __restrict__ cwp1,
    float* __restrict__ out)
{
  __shared__ __align__(16) unsigned short Pt[2][64][140];
  const int t = threadIdx.x, w = t >> 6, lane = t & 63;
  const int lo4 = lane & 15, hi4 = lane >> 4;
  const int b = blockIdx.y, mb = blockIdx.x * 64;
  const float L2E = 1.4426950408889634f;

  short8 qh[4], ql[4];
  float sub[4];
#pragma unroll
  for (int mt = 0; mt < 4; ++mt) {
    const int m = mb + mt * 16 + lo4;
    const LL qa = ((LL)(b * 4096 + m)) * 32 + hi4 * 8;
    qh[mt] = *(const short8*)(qh_g + qa);
    ql[mt] = *(const short8*)(ql_g + qa);
    sub[mt] = subb[b * 4096 + m];
  }

  f32x4 acc[4][4];   // [ct][mt]
#pragma unroll
  for (int ct = 0; ct < 4; ++ct)
#pragma unroll
    for (int mt = 0; mt < 4; ++mt) acc[ct][mt] = (f32x4){0.f, 0.f, 0.f, 0.f};

  // K fragments for nt=0
  short8 kh[2], kl[2];
#pragma unroll
  for (int ns = 0; ns < 2; ++ns) {
    const LL ka = ((LL)(b * 1024 + w * 32 + ns * 16 + lo4)) * 32 + hi4 * 8;
    kh[ns] = *(const short8*)(kh_g + ka);
    kl[ns] = *(const short8*)(kl_g + ka);
  }

  int buf = 0;
  for (int nt = 0; nt < 8; ++nt) {
    // V prefetch for ks=0,1 (independent of everything this nt)
    short8 vpre[2][4];
#pragma unroll
    for (int ks = 0; ks < 2; ++ks)
#pragma unroll
      for (int ct = 0; ct < 4; ++ct)
        vpre[ks][ct] = *(const short8*)(
            v16 + (((LL)b * 32 + nt * 4 + ks) * 256 + w * 64 + ct * 16 + lo4) * 32 + hi4 * 8);
    // prefetch next-nt K (wraps at 7; harmless dummy)
    short8 knh[2], knl[2];
    {
      const int ntn = (nt + 1) & 7;
#pragma unroll
      for (int ns = 0; ns < 2; ++ns) {
        const LL ka = ((LL)(b * 1024 + ntn * 128 + w * 32 + ns * 16 + lo4)) * 32 + hi4 * 8;
        knh[ns] = *(const short8*)(kh_g + ka);
        knl[ns] = *(const short8*)(kl_g + ka);
      }
    }
    // logits + softmax + pack, per ns (short register live ranges)
#pragma unroll
    for (int ns = 0; ns < 2; ++ns) {
      f32x4 s[4];
#pragma unroll
      for (int mt = 0; mt < 4; ++mt) {
        f32x4 z = {0.f, 0.f, 0.f, 0.f};
        z = MFMA16(kl[ns], qh[mt], z);
        z = MFMA16(kh[ns], ql[mt], z);
        z = MFMA16(kh[ns], qh[mt], z);
        s[mt] = z;
      }
      const int nl = w * 32 + ns * 16 + hi4 * 4;
#pragma unroll
      for (int mt = 0; mt < 4; ++mt) {
        const int m_loc = mt * 16 + lo4;
        float p0 = exp2f(fmaf(s[mt][0], L2E, sub[mt]));
        float p1 = exp2f(fmaf(s[mt][1], L2E, sub[mt]));
        float p2 = exp2f(fmaf(s[mt][2], L2E, sub[mt]));
        float p3 = exp2f(fmaf(s[mt][3], L2E, sub[mt]));
        uint2v u;
        u[0] = (unsigned)f2bf(p0) | ((unsigned)f2bf(p1) << 16);
        u[1] = (unsigned)f2bf(p2) | ((unsigned)f2bf(p3) << 16);
        *(uint2v*)&Pt[buf][m_loc][nl] = u;
      }
    }
    __syncthreads();
    // PV
#pragma unroll
    for (int ks = 0; ks < 4; ++ks) {
      short8 pb[4];
#pragma unroll
      for (int mt = 0; mt < 4; ++mt)
        pb[mt] = *(const short8*)&Pt[buf][mt * 16 + lo4][ks * 32 + hi4 * 8];
#pragma unroll
      for (int ct = 0; ct < 4; ++ct) {
        const short8 va = (ks < 2)
            ? vpre[ks][ct]
            : *(const short8*)(
                  v16 + (((LL)b * 32 + nt * 4 + ks) * 256 + w * 64 + ct * 16 + lo4) * 32 + hi4 * 8);
#pragma unroll
        for (int mt = 0; mt < 4; ++mt)
          acc[ct][mt] = MFMA16(va, pb[mt], acc[ct][mt]);
      }
    }
    buf ^= 1;
#pragma unroll
    for (int ns = 0; ns < 2; ++ns) { kh[ns] = knh[ns]; kl[ns] = knl[ns]; }
  }

#pragma unroll
  for (int ct = 0; ct < 4; ++ct)
#pragma unroll
    for (int mt = 0; mt < 4; ++mt) {
      const int m = mb + mt * 16 + lo4;
#pragma unroll
      for (int r = 0; r < 4; ++r) {
        const int c = w * 64 + ct * 16 + hi4 * 4 + r;
        const float cw = cwp1[b * 256 + c];
        const LL off = ((LL)(b * 256 + c)) * 4096 + m;
        out[off] = acc[ct][mt][r] + x1[off] * cw;
      }
    }
}

// ======================================================================
// launch
// ======================================================================
extern "C" void kernel_launch(void* const* d_in, const int* in_sizes, int n_in,
                              void* d_out, int out_size, void* d_ws, size_t ws_size,
                              hipStream_t stream) {
  const float* x1  = (const float*)d_in[0];
  const float* x2  = (const float*)d_in[1];
  const float* wq  = (const float*)d_in[2];
  const float* wk  = (const float*)d_in[3];
  const float* wv  = (const float*)d_in[4];
  const float* wc  = (const float*)d_in[5];
  const float* wch = (const float*)d_in[6];
  const float* wt1 = (const float*)d_in[7];
  const float* bt1 = (const float*)d_in[8];
  const float* lng = (const float*)d_in[9];
  const float* lnb = (const float*)d_in[10];
  const float* wt2 = (const float*)d_in[11];
  const float* bt2 = (const float*)d_in[12];
  float* outp = (float*)d_out;

  // ---- workspace (carve floats first, then shorts) ----
  float* ws   = (float*)d_ws;
  float* qtf  = ws;                      // q bf16 hi/lo region: 1,048,576 f
  float* ktf  = qtf + 1048576;           // k bf16 hi/lo region:   262,144 f
  float* mxsb = ktf + 262144;            //    32,768 f (subb)
  float* invb = mxsb + 32768;            //    32,768 f (unused)
  float* cfr  = invb + 32768;            //    32,768 f
  float* cfs  = cfr + 32768;             //    32,768 f
  float* Tb   = cfs + 32768;             //    18,432 f
  float* cwb  = Tb + 18432;              //     2,048 f
  unsigned short* sbase = (unsigned short*)(cwb + 2048);
  unsigned short* v16  = sbase;          // CHUNKED [8][32][256][32]  2,097,152 sh
  unsigned short* x1th = v16  + 2097152; // [8][8][4096][32]     8,388,608 sh
  unsigned short* x1tl = x1th + 8388608;
  unsigned short* x2th = x1tl + 8388608; // [8][16][1024][32]    4,194,304 sh
  unsigned short* x2tl = x2th + 4194304;
  unsigned short* wvt  = x2tl + 4194304; // [9][16][256][32]     1,179,648 sh
  unsigned short* wqh  = wvt  + 1179648; // [9][8][32][32]          73,728 sh
  unsigned short* wql  = wqh  + 73728;
  unsigned short* wkh  = wql  + 73728;   // [9][16][32][32]        147,456 sh
  unsigned short* wkl  = wkh  + 147456;

  // bf16 hi/lo attn operands (alias the fp32 regions exactly):
  unsigned short* qhg = (unsigned short*)qtf;   // [8][4096][32] sh
  unsigned short* qlg = qhg + 1048576;
  unsigned short* khg = (unsigned short*)ktf;   // [8][1024][32] sh
  unsigned short* klg = khg + 262144;

  // ykern partial slab: [8][32][2304] f = 2.36 MB, aliases dead x2 region
  float* ykp = (float*)x2th;

  // weight pre-transforms ([9][IC/32][OC][32])
  wtrans2<<<dim3(4608), 256, 0, stream>>>(wv, wvt, nullptr, 256, 512);
  wtrans2<<<dim3(288),  256, 0, stream>>>(wq, wqh, wql, 32, 256);
  wtrans2<<<dim3(576),  256, 0, stream>>>(wk, wkh, wkl, 32, 512);

  // input transposes: [b][c][n] fp32 -> chunked [b][c/32][n][32] bf16 hi/lo
  transp<<<dim3(64, 4, 8), 256, 0, stream>>>(x1, x1th, x1tl, 256, 4096);
  transp<<<dim3(16, 8, 8), 256, 0, stream>>>(x2, x2th, x2tl, 512, 1024);

  // k conv (x2, C=512): 16 waves, full in-block K-split, direct bf16 out
  conv_qk_s<16><<<dim3(32, 1, 8), 1024, 0, stream>>>(
      x2th, x2tl, wkh, wkl, khg, klg, 5, 32);

  // v conv (x2): row-reuse register-tiled, 0.5 loads/MFMA
  conv_v_w<<<dim3(8, 4, 8), 512, 0, stream>>>(x2th, wvt, v16);

  // q conv (x1, C=256): 8 waves, full in-block K-split, direct bf16 out
  conv_qk_s<8><<<dim3(128, 1, 8), 512, 0, stream>>>(
      x1th, x1tl, wqh, wql, qhg, qlg, 6, 64);

  // channel branch (x2 region now dead -> ykp aliases it)
  cf_dot<<<dim3(16, 8), 256, 0, stream>>>(x1, wc, cfr);
  cf_softmax<<<dim3(8), 1024, 0, stream>>>(cfr, cfs);
  ykern2<<<dim3(32, 8), 512, 0, stream>>>(x1, cfs, ykp);
  red_t<<<dim3(3, 8), 256, 0, stream>>>(ykp, Tb);
  pool_k<<<dim3(32, 8), 256, 0, stream>>>(Tb, wch, cfr);
  chw_tail<<<dim3(8), 256, 0, stream>>>(cfr, wt1, bt1, lng, lnb, wt2, bt2, cwb);

  // attention
  attn_stats<<<dim3(64, 8), 256, 0, stream>>>(qhg, qlg, khg, klg, mxsb);
  attn_pv<<<dim3(64, 8), 256, 0, stream>>>(qhg, qlg, khg, klg, v16, mxsb, x1, cwb, outp);
}